// Round 1
// baseline (9185.904 us; speedup 1.0000x reference)
//
#include <hip/hip_runtime.h>
#include <hip/hip_bf16.h>
#include <math.h>

#define L_   8
#define D_   768
#define H_   12
#define V_   32000
#define B_   2
#define S_   1024
#define HD_  64
#define BS_  2048      // B_*S_
#define DFF_ 3072      // MR*D

// ---------------------------------------------------------------- embedding
__global__ __launch_bounds__(256) void k_embed(const int* __restrict__ tokens,
    const float* __restrict__ tok_emb, const float* __restrict__ pos_emb,
    float* __restrict__ x) {
  int idx = blockIdx.x * 256 + threadIdx.x;     // [0, BS_*D_)
  int row = idx / D_;                           // b*S + s
  int d   = idx - row * D_;
  int s   = row & (S_ - 1);
  int t   = tokens[row];
  x[idx] = tok_emb[(size_t)t * D_ + d] + pos_emb[(size_t)s * D_ + d];
}

// ---------------------------------------------------------------- layernorm
__global__ __launch_bounds__(256) void k_ln(const float* __restrict__ x,
    const float* __restrict__ g, const float* __restrict__ b,
    float* __restrict__ out) {
  int row = blockIdx.x;
  const float* xr = x + (size_t)row * D_;
  int t = threadIdx.x;
  float v0 = xr[t], v1 = xr[t + 256], v2 = xr[t + 512];
  float s  = v0 + v1 + v2;
  float s2 = v0 * v0 + v1 * v1 + v2 * v2;
#pragma unroll
  for (int off = 32; off; off >>= 1) {
    s  += __shfl_down(s, off);
    s2 += __shfl_down(s2, off);
  }
  __shared__ float rs[4], rs2[4];
  __shared__ float mean_s, rstd_s;
  int wid = t >> 6;
  if ((t & 63) == 0) { rs[wid] = s; rs2[wid] = s2; }
  __syncthreads();
  if (t == 0) {
    float S1 = rs[0] + rs[1] + rs[2] + rs[3];
    float S2 = rs2[0] + rs2[1] + rs2[2] + rs2[3];
    float m  = S1 / D_;
    float var = S2 / D_ - m * m;
    mean_s = m;
    rstd_s = rsqrtf(var + 1e-5f);
  }
  __syncthreads();
  float m = mean_s, r = rstd_s;
  float* orow = out + (size_t)row * D_;
  orow[t]       = (v0 - m) * r * g[t]       + b[t];
  orow[t + 256] = (v1 - m) * r * g[t + 256] + b[t + 256];
  orow[t + 512] = (v2 - m) * r * g[t + 512] + b[t + 512];
}

// ---------------------------------------------------------------- GEMM
// C[M,N] = A[M,K] @ W[K,N] + bias[N] (+ resid) (+ gelu). 64x64 tile, BK=16.
template <int ACT>
__global__ __launch_bounds__(256) void k_gemm(const float* __restrict__ A,
    const float* __restrict__ W, const float* __restrict__ bias,
    const float* __restrict__ resid, float* __restrict__ C,
    int M, int N, int K) {
  __shared__ __align__(16) float As[16][68];
  __shared__ __align__(16) float Ws[16][68];
  const int tid = threadIdx.x;
  const int m0 = blockIdx.y * 64, n0 = blockIdx.x * 64;
  const int tx = tid & 15, ty = tid >> 4;
  const int arow = tid >> 2, acol = (tid & 3) * 4;   // A tile 64x16
  const int wrow = tid >> 4, wcol = (tid & 15) * 4;  // W tile 16x64
  float acc[4][4] = {};
  for (int k0 = 0; k0 < K; k0 += 16) {
    float4 av = *reinterpret_cast<const float4*>(A + (size_t)(m0 + arow) * K + k0 + acol);
    As[acol + 0][arow] = av.x; As[acol + 1][arow] = av.y;
    As[acol + 2][arow] = av.z; As[acol + 3][arow] = av.w;
    float4 wv = *reinterpret_cast<const float4*>(W + (size_t)(k0 + wrow) * N + n0 + wcol);
    *reinterpret_cast<float4*>(&Ws[wrow][wcol]) = wv;
    __syncthreads();
#pragma unroll
    for (int kk = 0; kk < 16; kk++) {
      float4 a4 = *reinterpret_cast<const float4*>(&As[kk][ty * 4]);
      float4 w4 = *reinterpret_cast<const float4*>(&Ws[kk][tx * 4]);
      float aa[4] = {a4.x, a4.y, a4.z, a4.w};
      float ww[4] = {w4.x, w4.y, w4.z, w4.w};
#pragma unroll
      for (int i = 0; i < 4; i++)
#pragma unroll
        for (int j = 0; j < 4; j++) acc[i][j] += aa[i] * ww[j];
    }
    __syncthreads();
  }
#pragma unroll
  for (int i = 0; i < 4; i++) {
    int m = m0 + ty * 4 + i;
#pragma unroll
    for (int j = 0; j < 4; j++) {
      int n = n0 + tx * 4 + j;
      float vv = acc[i][j] + bias[n];
      if (resid) vv += resid[(size_t)m * N + n];
      if (ACT == 1) vv = 0.5f * vv * (1.0f + erff(vv * 0.70710678118654752f));
      C[(size_t)m * N + n] = vv;
    }
  }
}

// ---------------------------------------------------------------- attention
// One block per (b*H+h, 16-query tile). Scores kept in LDS: 1024 causal keys
// + up to 7 "memory" logits (k_col of previous layers at the SAME position).
__global__ __launch_bounds__(256) void k_attn(
    const float* __restrict__ q_row, const float* __restrict__ k_row,
    const float* __restrict__ v_row, const float* __restrict__ q_col,
    const float* __restrict__ mem_k, const float* __restrict__ mem_v,
    float* __restrict__ ctx, int layer) {
  const int bh = blockIdx.x;
  const int b  = bh / H_, hh = bh % H_;
  const int q0 = blockIdx.y * 16;
  const int tid = threadIdx.x;
  const float inv = 0.125f;  // 1/sqrt(64)

  __shared__ float Q[16][65];
  __shared__ float Qc[16][65];
  __shared__ float KV[64][65];
  __shared__ float Sl[16][1032];

  // stage Q and Qc (16 x 64)
  {
    int r = tid >> 4, c = (tid & 15) * 4;
    size_t base = ((size_t)(b * S_ + q0 + r)) * D_ + hh * HD_ + c;
    float4 a = *reinterpret_cast<const float4*>(q_row + base);
    Q[r][c] = a.x; Q[r][c + 1] = a.y; Q[r][c + 2] = a.z; Q[r][c + 3] = a.w;
    float4 c4 = *reinterpret_cast<const float4*>(q_col + base);
    Qc[r][c] = c4.x; Qc[r][c + 1] = c4.y; Qc[r][c + 2] = c4.z; Qc[r][c + 3] = c4.w;
  }

  const int ktmax = (q0 + 15) >> 6;  // inclusive; k0 <= 960 so rows always < S

  // ---- phase 1: token scores
  {
    const int q = tid >> 4, kbase = tid & 15;
    const int qabs = q0 + q;
    for (int kt = 0; kt <= ktmax; kt++) {
      int k0 = kt * 64;
      __syncthreads();  // previous tile fully consumed (also covers Q staging)
      for (int rr = 0; rr < 64; rr += 16) {
        int r = rr + (tid >> 4), c = (tid & 15) * 4;
        float4 kv = *reinterpret_cast<const float4*>(
            k_row + ((size_t)(b * S_ + k0 + r)) * D_ + hh * HD_ + c);
        KV[r][c] = kv.x; KV[r][c + 1] = kv.y; KV[r][c + 2] = kv.z; KV[r][c + 3] = kv.w;
      }
      __syncthreads();
      float sacc[4] = {0.f, 0.f, 0.f, 0.f};
      for (int d = 0; d < 64; d++) {
        float qv = Q[q][d];
#pragma unroll
        for (int j = 0; j < 4; j++) sacc[j] += qv * KV[kbase + 16 * j][d];
      }
#pragma unroll
      for (int j = 0; j < 4; j++) {
        int kabs = k0 + kbase + 16 * j;
        Sl[q][kabs] = (kabs <= qabs) ? sacc[j] * inv : -INFINITY;
      }
    }
  }
  __syncthreads();

  // ---- memory logits: l < layer, key/value at same position qabs
  if ((tid & 15) < layer) {
    int q = tid >> 4, l = tid & 15;
    int qabs = q0 + q;
    const float* kp = mem_k + ((size_t)l * BS_ + b * S_ + qabs) * D_ + hh * HD_;
    float s_ = 0.f;
    for (int d = 0; d < 64; d++) s_ += Qc[q][d] * kp[d];
    Sl[q][1024 + l] = s_ * inv;
  }
  __syncthreads();

  // ---- phase 2: softmax over [0..qabs] ++ [1024..1024+layer)
  {
    int r = tid >> 4, t16 = tid & 15;
    int qabs = q0 + r;
    float mx = -INFINITY;
    for (int kk = t16; kk <= qabs; kk += 16) mx = fmaxf(mx, Sl[r][kk]);
    if (t16 < layer) mx = fmaxf(mx, Sl[r][1024 + t16]);
#pragma unroll
    for (int off = 8; off; off >>= 1) mx = fmaxf(mx, __shfl_xor(mx, off, 16));
    float den = 0.f;
    for (int kk = t16; kk <= qabs; kk += 16) {
      float e = __expf(Sl[r][kk] - mx);
      Sl[r][kk] = e; den += e;
    }
    if (t16 < layer) {
      float e = __expf(Sl[r][1024 + t16] - mx);
      Sl[r][1024 + t16] = e; den += e;
    }
#pragma unroll
    for (int off = 8; off; off >>= 1) den += __shfl_xor(den, off, 16);
    float rden = 1.f / den;
    for (int kk = t16; kk <= qabs; kk += 16) Sl[r][kk] *= rden;
    if (t16 < layer) Sl[r][1024 + t16] *= rden;
  }

  // ---- phase 3: ctx = P @ V  (+ memory V)
  {
    const int q = tid >> 4;
    const int dbase = (tid & 15) * 4;
    const int qabs = q0 + q;
    float a0 = 0.f, a1 = 0.f, a2 = 0.f, a3 = 0.f;
    for (int kt = 0; kt <= ktmax; kt++) {
      int k0 = kt * 64;
      __syncthreads();  // previous V tile consumed / softmax done
      for (int rr = 0; rr < 64; rr += 16) {
        int r = rr + (tid >> 4), c = (tid & 15) * 4;
        float4 vv = *reinterpret_cast<const float4*>(
            v_row + ((size_t)(b * S_ + k0 + r)) * D_ + hh * HD_ + c);
        KV[r][c] = vv.x; KV[r][c + 1] = vv.y; KV[r][c + 2] = vv.z; KV[r][c + 3] = vv.w;
      }
      __syncthreads();
      int kmax = qabs - k0; if (kmax > 63) kmax = 63;
      for (int kk = 0; kk <= kmax; kk++) {
        float w = Sl[q][k0 + kk];
        a0 += w * KV[kk][dbase];     a1 += w * KV[kk][dbase + 1];
        a2 += w * KV[kk][dbase + 2]; a3 += w * KV[kk][dbase + 3];
      }
    }
    for (int l = 0; l < layer; l++) {
      float w = Sl[q][1024 + l];
      const float* vp = mem_v + ((size_t)l * BS_ + b * S_ + qabs) * D_ + hh * HD_ + dbase;
      a0 += w * vp[0]; a1 += w * vp[1]; a2 += w * vp[2]; a3 += w * vp[3];
    }
    float* cp = ctx + ((size_t)(b * S_ + qabs)) * D_ + hh * HD_ + dbase;
    cp[0] = a0; cp[1] = a1; cp[2] = a2; cp[3] = a3;
  }
}

// ---------------------------------------------------------------- launch
extern "C" void kernel_launch(void* const* d_in, const int* in_sizes, int n_in,
                              void* d_out, int out_size, void* d_ws, size_t ws_size,
                              hipStream_t stream) {
  const int*   tokens  = (const int*)d_in[0];
  const float* tok_emb = (const float*)d_in[1];
  const float* pos_emb = (const float*)d_in[2];
  const float *Wq_row, *Wk_row, *Wv_row, *Wq_col, *Wo;
  const float *bq_row, *bk_row, *bv_row, *bq_col, *bo;
  if (in_sizes[4] == L_ * D_ * D_) {  // dict order
    Wq_row = (const float*)d_in[3];  Wk_row = (const float*)d_in[4];
    Wv_row = (const float*)d_in[5];  Wq_col = (const float*)d_in[6];
    Wo     = (const float*)d_in[7];
    bq_row = (const float*)d_in[8];  bk_row = (const float*)d_in[9];
    bv_row = (const float*)d_in[10]; bq_col = (const float*)d_in[11];
    bo     = (const float*)d_in[12];
  } else {  // signature order fallback
    Wq_row = (const float*)d_in[3];  bq_row = (const float*)d_in[4];
    Wk_row = (const float*)d_in[5];  bk_row = (const float*)d_in[6];
    Wv_row = (const float*)d_in[7];  bv_row = (const float*)d_in[8];
    Wq_col = (const float*)d_in[9];  bq_col = (const float*)d_in[10];
    Wo     = (const float*)d_in[11]; bo     = (const float*)d_in[12];
  }
  const float* ln1_g = (const float*)d_in[13]; const float* ln1_b = (const float*)d_in[14];
  const float* ln2_g = (const float*)d_in[15]; const float* ln2_b = (const float*)d_in[16];
  const float* W1    = (const float*)d_in[17]; const float* b1    = (const float*)d_in[18];
  const float* W2    = (const float*)d_in[19]; const float* b2    = (const float*)d_in[20];
  const float* Wk_sh = (const float*)d_in[21]; const float* bk_sh = (const float*)d_in[22];
  const float* Wv_sh = (const float*)d_in[23]; const float* bv_sh = (const float*)d_in[24];
  const float* lnf_g = (const float*)d_in[25]; const float* lnf_b = (const float*)d_in[26];
  const float* Whead = (const float*)d_in[27]; const float* bhead = (const float*)d_in[28];

  // workspace layout (f32): ~170 MB
  float* wsp = (float*)d_ws;
  float* x    = wsp; wsp += (size_t)BS_ * D_;
  float* h    = wsp; wsp += (size_t)BS_ * D_;
  float* qb   = wsp; wsp += (size_t)BS_ * D_;
  float* kb   = wsp; wsp += (size_t)BS_ * D_;
  float* vb   = wsp; wsp += (size_t)BS_ * D_;
  float* qcb  = wsp; wsp += (size_t)BS_ * D_;
  float* ctxb = wsp; wsp += (size_t)BS_ * D_;
  float* mlpb = wsp; wsp += (size_t)BS_ * DFF_;
  float* mem_k = wsp; wsp += (size_t)L_ * BS_ * D_;
  float* mem_v = wsp; wsp += (size_t)L_ * BS_ * D_;

  k_embed<<<dim3((BS_ * D_) / 256), 256, 0, stream>>>(tokens, tok_emb, pos_emb, x);

  const dim3 gD(D_ / 64, BS_ / 64);     // 12 x 32
  const dim3 gF(DFF_ / 64, BS_ / 64);   // 48 x 32
  for (int i = 0; i < L_; i++) {
    k_ln<<<dim3(BS_), 256, 0, stream>>>(x, ln1_g + i * D_, ln1_b + i * D_, h);
    k_gemm<0><<<gD, 256, 0, stream>>>(h, Wq_row + (size_t)i * D_ * D_, bq_row + i * D_, nullptr, qb,  BS_, D_, D_);
    k_gemm<0><<<gD, 256, 0, stream>>>(h, Wk_row + (size_t)i * D_ * D_, bk_row + i * D_, nullptr, kb,  BS_, D_, D_);
    k_gemm<0><<<gD, 256, 0, stream>>>(h, Wv_row + (size_t)i * D_ * D_, bv_row + i * D_, nullptr, vb,  BS_, D_, D_);
    k_gemm<0><<<gD, 256, 0, stream>>>(h, Wq_col + (size_t)i * D_ * D_, bq_col + i * D_, nullptr, qcb, BS_, D_, D_);
    k_gemm<0><<<gD, 256, 0, stream>>>(h, Wk_sh, bk_sh, nullptr, mem_k + (size_t)i * BS_ * D_, BS_, D_, D_);
    k_gemm<0><<<gD, 256, 0, stream>>>(h, Wv_sh, bv_sh, nullptr, mem_v + (size_t)i * BS_ * D_, BS_, D_, D_);
    k_attn<<<dim3(B_ * H_, S_ / 16), 256, 0, stream>>>(qb, kb, vb, qcb, mem_k, mem_v, ctxb, i);
    k_gemm<0><<<gD, 256, 0, stream>>>(ctxb, Wo + (size_t)i * D_ * D_, bo + i * D_, x, x, BS_, D_, D_);
    k_ln<<<dim3(BS_), 256, 0, stream>>>(x, ln2_g + i * D_, ln2_b + i * D_, h);
    k_gemm<1><<<gF, 256, 0, stream>>>(h, W1 + (size_t)i * D_ * DFF_, b1 + (size_t)i * DFF_, nullptr, mlpb, BS_, DFF_, D_);
    k_gemm<0><<<gD, 256, 0, stream>>>(mlpb, W2 + (size_t)i * DFF_ * D_, b2 + i * D_, x, x, BS_, D_, DFF_);
  }
  k_ln<<<dim3(BS_), 256, 0, stream>>>(x, lnf_g, lnf_b, h);
  k_gemm<0><<<dim3(V_ / 64, BS_ / 64), 256, 0, stream>>>(h, Whead, bhead, nullptr, (float*)d_out, BS_, V_, D_);
}

// Round 2
// 4803.672 us; speedup vs baseline: 1.9123x; 1.9123x over previous
//
#include <hip/hip_runtime.h>
#include <hip/hip_bf16.h>
#include <math.h>

#define L_   8
#define D_   768
#define H_   12
#define V_   32000
#define B_   2
#define S_   1024
#define HD_  64
#define BS_  2048      // B_*S_
#define DFF_ 3072      // MR*D

typedef __hip_bfloat16 bf16;
typedef __attribute__((ext_vector_type(8))) short bf16x8;
typedef __attribute__((ext_vector_type(4))) float f32x4;

#define CFUN(r) ((((r) & 3)) ^ (((r) >> 2) & 3))

__device__ __forceinline__ void cp16(void* lds, const void* g) {
  __builtin_amdgcn_global_load_lds(
      (const __attribute__((address_space(1))) void*)g,
      (__attribute__((address_space(3))) void*)lds, 16, 0, 0);
}

// ---------------------------------------------------------------- embedding
__global__ __launch_bounds__(256) void k_embed(const int* __restrict__ tokens,
    const float* __restrict__ tok_emb, const float* __restrict__ pos_emb,
    float* __restrict__ x) {
  int idx = blockIdx.x * 256 + threadIdx.x;
  int row = idx / D_;
  int d   = idx - row * D_;
  int s   = row & (S_ - 1);
  int t   = tokens[row];
  x[idx] = tok_emb[(size_t)t * D_ + d] + pos_emb[(size_t)s * D_ + d];
}

// ---------------------------------------------------------------- layernorm -> bf16
__global__ __launch_bounds__(256) void k_ln(const float* __restrict__ x,
    const float* __restrict__ g, const float* __restrict__ b,
    bf16* __restrict__ out) {
  int row = blockIdx.x;
  const float* xr = x + (size_t)row * D_;
  int t = threadIdx.x;
  float v0 = xr[t], v1 = xr[t + 256], v2 = xr[t + 512];
  float s  = v0 + v1 + v2;
  float s2 = v0 * v0 + v1 * v1 + v2 * v2;
#pragma unroll
  for (int off = 32; off; off >>= 1) {
    s  += __shfl_down(s, off);
    s2 += __shfl_down(s2, off);
  }
  __shared__ float rs[4], rs2[4];
  __shared__ float mean_s, rstd_s;
  int wid = t >> 6;
  if ((t & 63) == 0) { rs[wid] = s; rs2[wid] = s2; }
  __syncthreads();
  if (t == 0) {
    float S1 = rs[0] + rs[1] + rs[2] + rs[3];
    float S2 = rs2[0] + rs2[1] + rs2[2] + rs2[3];
    float m  = S1 / D_;
    float var = S2 / D_ - m * m;
    mean_s = m;
    rstd_s = rsqrtf(var + 1e-5f);
  }
  __syncthreads();
  float m = mean_s, r = rstd_s;
  bf16* orow = out + (size_t)row * D_;
  orow[t]       = __float2bfloat16((v0 - m) * r * g[t]       + b[t]);
  orow[t + 256] = __float2bfloat16((v1 - m) * r * g[t + 256] + b[t + 256]);
  orow[t + 512] = __float2bfloat16((v2 - m) * r * g[t + 512] + b[t + 512]);
}

// ------------------------------------------------- weight convert + transpose
// W[K][N] f32 -> Wt[N][K] bf16. grid (N/32, K/32, nmat), block (32,8).
__global__ __launch_bounds__(256) void k_w2bf_t(const float* __restrict__ W,
    bf16* __restrict__ Wt, int K, int N) {
  __shared__ float t[32][33];
  const float* Wm = W + (size_t)blockIdx.z * K * N;
  bf16* Wtm = Wt + (size_t)blockIdx.z * K * N;
  int n0 = blockIdx.x * 32, k0 = blockIdx.y * 32;
  int tx = threadIdx.x;
  for (int i = threadIdx.y; i < 32; i += 8)
    t[i][tx] = Wm[(size_t)(k0 + i) * N + n0 + tx];
  __syncthreads();
  for (int i = threadIdx.y; i < 32; i += 8)
    Wtm[(size_t)(n0 + i) * K + k0 + tx] = __float2bfloat16(t[tx][i]);
}

// ---------------------------------------------------------------- bf16 MFMA GEMM
// C[M,N] = A[M,K](bf16) @ Wt[N,K](bf16)^T + bias. 128x128 tile, BK=32, 4 waves.
// EPI: 0 = f32 out + bias; 1 = f32 out + bias + resid; 2 = bf16 out + bias + gelu
template <int EPI>
__global__ __launch_bounds__(256) void k_bgemm(
    const bf16* __restrict__ A, const bf16* __restrict__ Wt,
    const float* __restrict__ bias, const float* __restrict__ resid,
    float* __restrict__ Cf, bf16* __restrict__ Cb,
    int M, int N, int K) {
  __shared__ __align__(16) char smem[16384];
  const int tid = threadIdx.x;
  const int l = tid & 63, w = tid >> 6;
  const int wr = w >> 1, wc = w & 1;
  const int m0 = blockIdx.y * 128, n0 = blockIdx.x * 128;
  const int lane15 = l & 15, lg = l >> 4;

  // staging: LDS granule (r,p) holds logical (r, p ^ c(r)); dest linear,
  // source address carries the swizzle (global_load_lds rule).
  const int G0 = w * 64 + l, G1 = 256 + w * 64 + l;
  const int r0 = G0 >> 2, p0 = G0 & 3;
  const int r1 = G1 >> 2, p1 = G1 & 3;
  const char* aSrc0 = (const char*)(A  + (size_t)(m0 + r0) * K) + ((p0 ^ CFUN(r0)) * 16);
  const char* aSrc1 = (const char*)(A  + (size_t)(m0 + r1) * K) + ((p1 ^ CFUN(r1)) * 16);
  const char* bSrc0 = (const char*)(Wt + (size_t)(n0 + r0) * K) + ((p0 ^ CFUN(r0)) * 16);
  const char* bSrc1 = (const char*)(Wt + (size_t)(n0 + r1) * K) + ((p1 ^ CFUN(r1)) * 16);
  char* ldsA0 = smem + w * 1024;           // wave-uniform bases
  char* ldsA1 = smem + 4096  + w * 1024;
  char* ldsB0 = smem + 8192  + w * 1024;
  char* ldsB1 = smem + 12288 + w * 1024;

  // fragment read byte-offsets (swizzled)
  int aOff[4], bOff[4];
#pragma unroll
  for (int mi = 0; mi < 4; mi++) {
    int r = wr * 64 + mi * 16 + lane15;
    aOff[mi] = r * 64 + ((lg ^ CFUN(r)) * 16);
  }
#pragma unroll
  for (int ni = 0; ni < 4; ni++) {
    int r = wc * 64 + ni * 16 + lane15;
    bOff[ni] = 8192 + r * 64 + ((lg ^ CFUN(r)) * 16);
  }

  f32x4 acc[4][4];
#pragma unroll
  for (int mi = 0; mi < 4; mi++)
#pragma unroll
    for (int ni = 0; ni < 4; ni++) acc[mi][ni] = (f32x4){0.f, 0.f, 0.f, 0.f};

  for (int k0 = 0; k0 < K; k0 += 32) {
    __syncthreads();                // all waves done reading previous tile
    const size_t kb = (size_t)k0 * 2;
    cp16(ldsA0, aSrc0 + kb);
    cp16(ldsA1, aSrc1 + kb);
    cp16(ldsB0, bSrc0 + kb);
    cp16(ldsB1, bSrc1 + kb);
    __syncthreads();                // drains vmcnt(0) before barrier
    bf16x8 af[4], bfr[4];
#pragma unroll
    for (int mi = 0; mi < 4; mi++) af[mi] = *(const bf16x8*)(smem + aOff[mi]);
#pragma unroll
    for (int ni = 0; ni < 4; ni++) bfr[ni] = *(const bf16x8*)(smem + bOff[ni]);
#pragma unroll
    for (int mi = 0; mi < 4; mi++)
#pragma unroll
      for (int ni = 0; ni < 4; ni++)
        acc[mi][ni] = __builtin_amdgcn_mfma_f32_16x16x32_bf16(
            af[mi], bfr[ni], acc[mi][ni], 0, 0, 0);
  }

#pragma unroll
  for (int ni = 0; ni < 4; ni++) {
    int col = n0 + wc * 64 + ni * 16 + lane15;
    float bv = bias[col];
#pragma unroll
    for (int mi = 0; mi < 4; mi++) {
      int rowb = m0 + wr * 64 + mi * 16 + lg * 4;
#pragma unroll
      for (int j = 0; j < 4; j++) {
        int row = rowb + j;
        float v = acc[mi][ni][j] + bv;
        if (EPI == 1) v += resid[(size_t)row * N + col];
        if (EPI == 2) {
          v = 0.5f * v * (1.0f + erff(v * 0.70710678118654752f));
          Cb[(size_t)row * N + col] = __float2bfloat16(v);
        } else {
          Cf[(size_t)row * N + col] = v;
        }
      }
    }
  }
}

// ---------------------------------------------------------------- attention
__global__ __launch_bounds__(256) void k_attn(
    const float* __restrict__ q_row, const float* __restrict__ k_row,
    const float* __restrict__ v_row, const float* __restrict__ q_col,
    const float* __restrict__ mem_k, const float* __restrict__ mem_v,
    bf16* __restrict__ ctx, int layer) {
  const int bh = blockIdx.x;
  const int b  = bh / H_, hh = bh % H_;
  const int q0 = blockIdx.y * 16;
  const int tid = threadIdx.x;
  const float inv = 0.125f;

  __shared__ float Q[16][65];
  __shared__ float Qc[16][65];
  __shared__ float KV[64][65];
  __shared__ float Sl[16][1032];

  {
    int r = tid >> 4, c = (tid & 15) * 4;
    size_t base = ((size_t)(b * S_ + q0 + r)) * D_ + hh * HD_ + c;
    float4 a = *reinterpret_cast<const float4*>(q_row + base);
    Q[r][c] = a.x; Q[r][c + 1] = a.y; Q[r][c + 2] = a.z; Q[r][c + 3] = a.w;
    float4 c4 = *reinterpret_cast<const float4*>(q_col + base);
    Qc[r][c] = c4.x; Qc[r][c + 1] = c4.y; Qc[r][c + 2] = c4.z; Qc[r][c + 3] = c4.w;
  }

  const int ktmax = (q0 + 15) >> 6;

  {
    const int q = tid >> 4, kbase = tid & 15;
    const int qabs = q0 + q;
    for (int kt = 0; kt <= ktmax; kt++) {
      int k0 = kt * 64;
      __syncthreads();
      for (int rr = 0; rr < 64; rr += 16) {
        int r = rr + (tid >> 4), c = (tid & 15) * 4;
        float4 kv = *reinterpret_cast<const float4*>(
            k_row + ((size_t)(b * S_ + k0 + r)) * D_ + hh * HD_ + c);
        KV[r][c] = kv.x; KV[r][c + 1] = kv.y; KV[r][c + 2] = kv.z; KV[r][c + 3] = kv.w;
      }
      __syncthreads();
      float sacc[4] = {0.f, 0.f, 0.f, 0.f};
      for (int d = 0; d < 64; d++) {
        float qv = Q[q][d];
#pragma unroll
        for (int j = 0; j < 4; j++) sacc[j] += qv * KV[kbase + 16 * j][d];
      }
#pragma unroll
      for (int j = 0; j < 4; j++) {
        int kabs = k0 + kbase + 16 * j;
        Sl[q][kabs] = (kabs <= qabs) ? sacc[j] * inv : -INFINITY;
      }
    }
  }
  __syncthreads();

  if ((tid & 15) < layer) {
    int q = tid >> 4, l = tid & 15;
    int qabs = q0 + q;
    const float* kp = mem_k + ((size_t)l * BS_ + b * S_ + qabs) * D_ + hh * HD_;
    float s_ = 0.f;
    for (int d = 0; d < 64; d++) s_ += Qc[q][d] * kp[d];
    Sl[q][1024 + l] = s_ * inv;
  }
  __syncthreads();

  {
    int r = tid >> 4, t16 = tid & 15;
    int qabs = q0 + r;
    float mx = -INFINITY;
    for (int kk = t16; kk <= qabs; kk += 16) mx = fmaxf(mx, Sl[r][kk]);
    if (t16 < layer) mx = fmaxf(mx, Sl[r][1024 + t16]);
#pragma unroll
    for (int off = 8; off; off >>= 1) mx = fmaxf(mx, __shfl_xor(mx, off, 16));
    float den = 0.f;
    for (int kk = t16; kk <= qabs; kk += 16) {
      float e = __expf(Sl[r][kk] - mx);
      Sl[r][kk] = e; den += e;
    }
    if (t16 < layer) {
      float e = __expf(Sl[r][1024 + t16] - mx);
      Sl[r][1024 + t16] = e; den += e;
    }
#pragma unroll
    for (int off = 8; off; off >>= 1) den += __shfl_xor(den, off, 16);
    float rden = 1.f / den;
    for (int kk = t16; kk <= qabs; kk += 16) Sl[r][kk] *= rden;
    if (t16 < layer) Sl[r][1024 + t16] *= rden;
  }

  {
    const int q = tid >> 4;
    const int dbase = (tid & 15) * 4;
    const int qabs = q0 + q;
    float a0 = 0.f, a1 = 0.f, a2 = 0.f, a3 = 0.f;
    for (int kt = 0; kt <= ktmax; kt++) {
      int k0 = kt * 64;
      __syncthreads();
      for (int rr = 0; rr < 64; rr += 16) {
        int r = rr + (tid >> 4), c = (tid & 15) * 4;
        float4 vv = *reinterpret_cast<const float4*>(
            v_row + ((size_t)(b * S_ + k0 + r)) * D_ + hh * HD_ + c);
        KV[r][c] = vv.x; KV[r][c + 1] = vv.y; KV[r][c + 2] = vv.z; KV[r][c + 3] = vv.w;
      }
      __syncthreads();
      int kmax = qabs - k0; if (kmax > 63) kmax = 63;
      for (int kk = 0; kk <= kmax; kk++) {
        float w = Sl[q][k0 + kk];
        a0 += w * KV[kk][dbase];     a1 += w * KV[kk][dbase + 1];
        a2 += w * KV[kk][dbase + 2]; a3 += w * KV[kk][dbase + 3];
      }
    }
    for (int l = 0; l < layer; l++) {
      float w = Sl[q][1024 + l];
      const float* vp = mem_v + ((size_t)l * BS_ + b * S_ + qabs) * D_ + hh * HD_ + dbase;
      a0 += w * vp[0]; a1 += w * vp[1]; a2 += w * vp[2]; a3 += w * vp[3];
    }
    bf16* cp = ctx + ((size_t)(b * S_ + qabs)) * D_ + hh * HD_ + dbase;
    cp[0] = __float2bfloat16(a0); cp[1] = __float2bfloat16(a1);
    cp[2] = __float2bfloat16(a2); cp[3] = __float2bfloat16(a3);
  }
}

// ---------------------------------------------------------------- launch
extern "C" void kernel_launch(void* const* d_in, const int* in_sizes, int n_in,
                              void* d_out, int out_size, void* d_ws, size_t ws_size,
                              hipStream_t stream) {
  const int*   tokens  = (const int*)d_in[0];
  const float* tok_emb = (const float*)d_in[1];
  const float* pos_emb = (const float*)d_in[2];
  const float *Wq_row, *Wk_row, *Wv_row, *Wq_col, *Wo;
  const float *bq_row, *bk_row, *bv_row, *bq_col, *bo;
  if (in_sizes[4] == L_ * D_ * D_) {  // dict order
    Wq_row = (const float*)d_in[3];  Wk_row = (const float*)d_in[4];
    Wv_row = (const float*)d_in[5];  Wq_col = (const float*)d_in[6];
    Wo     = (const float*)d_in[7];
    bq_row = (const float*)d_in[8];  bk_row = (const float*)d_in[9];
    bv_row = (const float*)d_in[10]; bq_col = (const float*)d_in[11];
    bo     = (const float*)d_in[12];
  } else {  // signature order fallback
    Wq_row = (const float*)d_in[3];  bq_row = (const float*)d_in[4];
    Wk_row = (const float*)d_in[5];  bk_row = (const float*)d_in[6];
    Wv_row = (const float*)d_in[7];  bv_row = (const float*)d_in[8];
    Wq_col = (const float*)d_in[9];  bq_col = (const float*)d_in[10];
    Wo     = (const float*)d_in[11]; bo     = (const float*)d_in[12];
  }
  const float* ln1_g = (const float*)d_in[13]; const float* ln1_b = (const float*)d_in[14];
  const float* ln2_g = (const float*)d_in[15]; const float* ln2_b = (const float*)d_in[16];
  const float* W1    = (const float*)d_in[17]; const float* b1    = (const float*)d_in[18];
  const float* W2    = (const float*)d_in[19]; const float* b2    = (const float*)d_in[20];
  const float* Wk_sh = (const float*)d_in[21]; const float* bk_sh = (const float*)d_in[22];
  const float* Wv_sh = (const float*)d_in[23]; const float* bv_sh = (const float*)d_in[24];
  const float* lnf_g = (const float*)d_in[25]; const float* lnf_b = (const float*)d_in[26];
  const float* Whead = (const float*)d_in[27]; const float* bhead = (const float*)d_in[28];

  // ---- workspace carve-up
  char* p = (char*)d_ws;
  float* x     = (float*)p; p += (size_t)BS_ * D_ * 4;
  float* qb    = (float*)p; p += (size_t)BS_ * D_ * 4;
  float* kb    = (float*)p; p += (size_t)BS_ * D_ * 4;
  float* vb    = (float*)p; p += (size_t)BS_ * D_ * 4;
  float* qcb   = (float*)p; p += (size_t)BS_ * D_ * 4;
  float* mem_k = (float*)p; p += (size_t)L_ * BS_ * D_ * 4;
  float* mem_v = (float*)p; p += (size_t)L_ * BS_ * D_ * 4;
  bf16* h_bf   = (bf16*)p; p += (size_t)BS_ * D_ * 2;
  bf16* ctx_bf = (bf16*)p; p += (size_t)BS_ * D_ * 2;
  bf16* mlp_bf = (bf16*)p; p += (size_t)BS_ * DFF_ * 2;
  bf16* tWq    = (bf16*)p; p += (size_t)L_ * D_ * D_ * 2;
  bf16* tWk    = (bf16*)p; p += (size_t)L_ * D_ * D_ * 2;
  bf16* tWv    = (bf16*)p; p += (size_t)L_ * D_ * D_ * 2;
  bf16* tWqc   = (bf16*)p; p += (size_t)L_ * D_ * D_ * 2;
  bf16* tWo    = (bf16*)p; p += (size_t)L_ * D_ * D_ * 2;
  bf16* tW1    = (bf16*)p; p += (size_t)L_ * D_ * DFF_ * 2;
  bf16* tW2    = (bf16*)p; p += (size_t)L_ * DFF_ * D_ * 2;
  bf16* tWksh  = (bf16*)p; p += (size_t)D_ * D_ * 2;
  bf16* tWvsh  = (bf16*)p; p += (size_t)D_ * D_ * 2;
  bf16* tWhead = (bf16*)p; p += (size_t)D_ * V_ * 2;

  // ---- weight conversion (every call; deterministic)
  dim3 tb(32, 8);
  k_w2bf_t<<<dim3(D_/32, D_/32, L_), tb, 0, stream>>>(Wq_row, tWq, D_, D_);
  k_w2bf_t<<<dim3(D_/32, D_/32, L_), tb, 0, stream>>>(Wk_row, tWk, D_, D_);
  k_w2bf_t<<<dim3(D_/32, D_/32, L_), tb, 0, stream>>>(Wv_row, tWv, D_, D_);
  k_w2bf_t<<<dim3(D_/32, D_/32, L_), tb, 0, stream>>>(Wq_col, tWqc, D_, D_);
  k_w2bf_t<<<dim3(D_/32, D_/32, L_), tb, 0, stream>>>(Wo, tWo, D_, D_);
  k_w2bf_t<<<dim3(DFF_/32, D_/32, L_), tb, 0, stream>>>(W1, tW1, D_, DFF_);
  k_w2bf_t<<<dim3(D_/32, DFF_/32, L_), tb, 0, stream>>>(W2, tW2, DFF_, D_);
  k_w2bf_t<<<dim3(D_/32, D_/32, 1), tb, 0, stream>>>(Wk_sh, tWksh, D_, D_);
  k_w2bf_t<<<dim3(D_/32, D_/32, 1), tb, 0, stream>>>(Wv_sh, tWvsh, D_, D_);
  k_w2bf_t<<<dim3(V_/32, D_/32, 1), tb, 0, stream>>>(Whead, tWhead, D_, V_);

  k_embed<<<dim3((BS_ * D_) / 256), 256, 0, stream>>>(tokens, tok_emb, pos_emb, x);

  const dim3 gD(D_ / 128, BS_ / 128);     // 6 x 16
  const dim3 gF(DFF_ / 128, BS_ / 128);   // 24 x 16
  for (int i = 0; i < L_; i++) {
    k_ln<<<dim3(BS_), 256, 0, stream>>>(x, ln1_g + i * D_, ln1_b + i * D_, h_bf);
    k_bgemm<0><<<gD, 256, 0, stream>>>(h_bf, tWq + (size_t)i*D_*D_, bq_row + i*D_, nullptr, qb,  nullptr, BS_, D_, D_);
    k_bgemm<0><<<gD, 256, 0, stream>>>(h_bf, tWk + (size_t)i*D_*D_, bk_row + i*D_, nullptr, kb,  nullptr, BS_, D_, D_);
    k_bgemm<0><<<gD, 256, 0, stream>>>(h_bf, tWv + (size_t)i*D_*D_, bv_row + i*D_, nullptr, vb,  nullptr, BS_, D_, D_);
    k_bgemm<0><<<gD, 256, 0, stream>>>(h_bf, tWqc + (size_t)i*D_*D_, bq_col + i*D_, nullptr, qcb, nullptr, BS_, D_, D_);
    k_bgemm<0><<<gD, 256, 0, stream>>>(h_bf, tWksh, bk_sh, nullptr, mem_k + (size_t)i*BS_*D_, nullptr, BS_, D_, D_);
    k_bgemm<0><<<gD, 256, 0, stream>>>(h_bf, tWvsh, bv_sh, nullptr, mem_v + (size_t)i*BS_*D_, nullptr, BS_, D_, D_);
    k_attn<<<dim3(B_ * H_, S_ / 16), 256, 0, stream>>>(qb, kb, vb, qcb, mem_k, mem_v, ctx_bf, i);
    k_bgemm<1><<<gD, 256, 0, stream>>>(ctx_bf, tWo + (size_t)i*D_*D_, bo + i*D_, x, x, nullptr, BS_, D_, D_);
    k_ln<<<dim3(BS_), 256, 0, stream>>>(x, ln2_g + i * D_, ln2_b + i * D_, h_bf);
    k_bgemm<2><<<gF, 256, 0, stream>>>(h_bf, tW1 + (size_t)i*D_*DFF_, b1 + (size_t)i*DFF_, nullptr, nullptr, mlp_bf, BS_, DFF_, D_);
    k_bgemm<1><<<gD, 256, 0, stream>>>(mlp_bf, tW2 + (size_t)i*DFF_*D_, b2 + i*D_, x, x, nullptr, BS_, D_, DFF_);
  }
  k_ln<<<dim3(BS_), 256, 0, stream>>>(x, lnf_g, lnf_b, h_bf);
  k_bgemm<0><<<dim3(V_ / 128, BS_ / 128), 256, 0, stream>>>(
      h_bf, tWhead, bhead, nullptr, (float*)d_out, nullptr, BS_, V_, D_);
}

// Round 3
// 2378.417 us; speedup vs baseline: 3.8622x; 2.0197x over previous
//
#include <hip/hip_runtime.h>
#include <hip/hip_bf16.h>
#include <math.h>

#define L_   8
#define D_   768
#define H_   12
#define V_   32000
#define B_   2
#define S_   1024
#define HD_  64
#define BS_  2048      // B_*S_
#define DFF_ 3072      // MR*D

typedef __hip_bfloat16 bf16;
typedef __attribute__((ext_vector_type(8))) short bf16x8;
typedef __attribute__((ext_vector_type(4))) float f32x4;

#define CFUN(r) ((((r) & 3)) ^ (((r) >> 2) & 3))

__device__ __forceinline__ void cp16(void* lds, const void* g) {
  __builtin_amdgcn_global_load_lds(
      (const __attribute__((address_space(1))) void*)g,
      (__attribute__((address_space(3))) void*)lds, 16, 0, 0);
}

__device__ __forceinline__ unsigned short f2bf(float v) {
  __hip_bfloat16 h = __float2bfloat16(v);
  return *reinterpret_cast<unsigned short*>(&h);
}
__device__ __forceinline__ float bf2f(unsigned short u) {
  return __uint_as_float(((unsigned)u) << 16);
}

// ---------------------------------------------------------------- embedding
__global__ __launch_bounds__(256) void k_embed(const int* __restrict__ tokens,
    const float* __restrict__ tok_emb, const float* __restrict__ pos_emb,
    float* __restrict__ x) {
  int idx = blockIdx.x * 256 + threadIdx.x;
  int row = idx / D_;
  int d   = idx - row * D_;
  int s   = row & (S_ - 1);
  int t   = tokens[row];
  x[idx] = tok_emb[(size_t)t * D_ + d] + pos_emb[(size_t)s * D_ + d];
}

// ---------------------------------------------------------------- layernorm -> bf16
__global__ __launch_bounds__(256) void k_ln(const float* __restrict__ x,
    const float* __restrict__ g, const float* __restrict__ b,
    bf16* __restrict__ out) {
  int row = blockIdx.x;
  const float* xr = x + (size_t)row * D_;
  int t = threadIdx.x;
  float v0 = xr[t], v1 = xr[t + 256], v2 = xr[t + 512];
  float s  = v0 + v1 + v2;
  float s2 = v0 * v0 + v1 * v1 + v2 * v2;
#pragma unroll
  for (int off = 32; off; off >>= 1) {
    s  += __shfl_down(s, off);
    s2 += __shfl_down(s2, off);
  }
  __shared__ float rs[4], rs2[4];
  __shared__ float mean_s, rstd_s;
  int wid = t >> 6;
  if ((t & 63) == 0) { rs[wid] = s; rs2[wid] = s2; }
  __syncthreads();
  if (t == 0) {
    float S1 = rs[0] + rs[1] + rs[2] + rs[3];
    float S2 = rs2[0] + rs2[1] + rs2[2] + rs2[3];
    float m  = S1 / D_;
    float var = S2 / D_ - m * m;
    mean_s = m;
    rstd_s = rsqrtf(var + 1e-5f);
  }
  __syncthreads();
  float m = mean_s, r = rstd_s;
  bf16* orow = out + (size_t)row * D_;
  orow[t]       = __float2bfloat16((v0 - m) * r * g[t]       + b[t]);
  orow[t + 256] = __float2bfloat16((v1 - m) * r * g[t + 256] + b[t + 256]);
  orow[t + 512] = __float2bfloat16((v2 - m) * r * g[t + 512] + b[t + 512]);
}

// ------------------------------------------------- weight convert + transpose
// W[K][N] f32 -> Wt[N][K] bf16 (slice-capable). grid (N/32, K/32, nz).
__global__ __launch_bounds__(256) void k_w2bf_t(const float* __restrict__ W,
    bf16* __restrict__ Wt, int K, int N, size_t ils, size_t ols) {
  __shared__ float t[32][33];
  const float* Wm = W + (size_t)blockIdx.z * ils;
  bf16* Wtm = Wt + (size_t)blockIdx.z * ols;
  int n0 = blockIdx.x * 32, k0 = blockIdx.y * 32;
  int tx = threadIdx.x;
  for (int i = threadIdx.y; i < 32; i += 8)
    t[i][tx] = Wm[(size_t)(k0 + i) * N + n0 + tx];
  __syncthreads();
  for (int i = threadIdx.y; i < 32; i += 8)
    Wtm[(size_t)(n0 + i) * K + k0 + tx] = __float2bfloat16(t[tx][i]);
}

// ---------------------------------------------------------------- bias concat
__global__ __launch_bounds__(256) void k_bcat(const float* __restrict__ bq,
    const float* __restrict__ bk, const float* __restrict__ bqc,
    const float* __restrict__ bksh, const float* __restrict__ bvsh,
    float* __restrict__ b3, float* __restrict__ bsh) {
  int idx = blockIdx.x * 256 + threadIdx.x;
  if (idx < L_ * 2304) {
    int l = idx / 2304, c = idx - l * 2304;
    float v = (c < 768) ? bq[l * 768 + c]
            : (c < 1536) ? bk[l * 768 + c - 768]
                         : bqc[l * 768 + c - 1536];
    b3[idx] = v;
  }
  if (idx < 1536) bsh[idx] = (idx < 768) ? bksh[idx] : bvsh[idx - 768];
}

// ---------------------------------------------------------------- bf16 MFMA GEMM
// C[M,N] = A[M,K](bf16) @ Wt[N,K](bf16)^T + bias. BMx128 tile, BK=32, 4 waves.
// EPI: 0 f32+bias; 1 f32+bias+resid; 2 bf16+bias+gelu; 3 bf16+bias;
//      5 bf16+bias, transposed into vT[b*768+col][s] (8B row-pack).
template <int BM, int EPI>
__global__ __launch_bounds__(256) void k_bgemm(
    const bf16* __restrict__ A, const bf16* __restrict__ Wt,
    const float* __restrict__ bias, const float* __restrict__ resid,
    float* __restrict__ Cf, bf16* __restrict__ Cb,
    int M, int N, int K) {
  constexpr int ABYTES = BM * 64;
  constexpr int MF = BM / 32;
  __shared__ __align__(16) char smem[ABYTES + 8192];
  const int tid = threadIdx.x;
  const int l = tid & 63, w = tid >> 6;
  const int wr = w >> 1, wc = w & 1;
  const int m0 = blockIdx.y * BM, n0 = blockIdx.x * 128;
  const int lane15 = l & 15, lg = l >> 4;

  const int r0 = tid >> 2, p0 = tid & 3;
  const int r1 = 64 + r0;
  const char* aSrc0 = (const char*)(A  + (size_t)(m0 + r0) * K) + ((p0 ^ CFUN(r0)) * 16);
  const char* aSrc1 = (const char*)(A  + (size_t)(m0 + r1) * K) + ((p0 ^ CFUN(r1)) * 16);
  const char* bSrc0 = (const char*)(Wt + (size_t)(n0 + r0) * K) + ((p0 ^ CFUN(r0)) * 16);
  const char* bSrc1 = (const char*)(Wt + (size_t)(n0 + r1) * K) + ((p0 ^ CFUN(r1)) * 16);
  char* ldsA0 = smem + w * 1024;
  char* ldsA1 = smem + 4096 + w * 1024;           // BM==128 only
  char* ldsB0 = smem + ABYTES + w * 1024;
  char* ldsB1 = smem + ABYTES + 4096 + w * 1024;

  int aOff[MF], bOff[4];
#pragma unroll
  for (int mi = 0; mi < MF; mi++) {
    int r = wr * (BM / 2) + mi * 16 + lane15;
    aOff[mi] = r * 64 + ((lg ^ CFUN(r)) * 16);
  }
#pragma unroll
  for (int ni = 0; ni < 4; ni++) {
    int r = wc * 64 + ni * 16 + lane15;
    bOff[ni] = ABYTES + r * 64 + ((lg ^ CFUN(r)) * 16);
  }

  f32x4 acc[MF][4];
#pragma unroll
  for (int mi = 0; mi < MF; mi++)
#pragma unroll
    for (int ni = 0; ni < 4; ni++) acc[mi][ni] = (f32x4){0.f, 0.f, 0.f, 0.f};

  for (int k0 = 0; k0 < K; k0 += 32) {
    __syncthreads();
    const size_t kb = (size_t)k0 * 2;
    cp16(ldsA0, aSrc0 + kb);
    if constexpr (BM == 128) cp16(ldsA1, aSrc1 + kb);
    cp16(ldsB0, bSrc0 + kb);
    cp16(ldsB1, bSrc1 + kb);
    __syncthreads();
    bf16x8 af[MF], bfr[4];
#pragma unroll
    for (int mi = 0; mi < MF; mi++) af[mi] = *(const bf16x8*)(smem + aOff[mi]);
#pragma unroll
    for (int ni = 0; ni < 4; ni++) bfr[ni] = *(const bf16x8*)(smem + bOff[ni]);
#pragma unroll
    for (int mi = 0; mi < MF; mi++)
#pragma unroll
      for (int ni = 0; ni < 4; ni++)
        acc[mi][ni] = __builtin_amdgcn_mfma_f32_16x16x32_bf16(
            af[mi], bfr[ni], acc[mi][ni], 0, 0, 0);
  }

#pragma unroll
  for (int ni = 0; ni < 4; ni++) {
    const int col = n0 + wc * 64 + ni * 16 + lane15;
    const float bv = bias[col];
#pragma unroll
    for (int mi = 0; mi < MF; mi++) {
      const int rowb = m0 + wr * (BM / 2) + mi * 16 + lg * 4;
      if constexpr (EPI == 5) {
        ushort4 pk;
        pk.x = f2bf(acc[mi][ni][0] + bv);
        pk.y = f2bf(acc[mi][ni][1] + bv);
        pk.z = f2bf(acc[mi][ni][2] + bv);
        pk.w = f2bf(acc[mi][ni][3] + bv);
        const int bq = rowb >> 10, s = rowb & (S_ - 1);
        *reinterpret_cast<ushort4*>(
            (unsigned short*)Cb + ((size_t)(bq * 768 + col)) * S_ + s) = pk;
      } else {
#pragma unroll
        for (int j = 0; j < 4; j++) {
          const int row = rowb + j;
          float v = acc[mi][ni][j] + bv;
          if constexpr (EPI == 1) v += resid[(size_t)row * N + col];
          if constexpr (EPI == 2) {
            v = 0.5f * v * (1.0f + erff(v * 0.70710678118654752f));
            Cb[(size_t)row * N + col] = __float2bfloat16(v);
          } else if constexpr (EPI == 3) {
            Cb[(size_t)row * N + col] = __float2bfloat16(v);
          } else {
            Cf[(size_t)row * N + col] = v;
          }
        }
      }
    }
  }
}

// ---------------------------------------------------------------- flash attention
// qkv [BS][2304] = q|k|qc (bf16). vT [B*768][S] bf16. memkv [L][BS][1536] = ksh|vsh.
// One wave handles 16 q-rows; 4 independent waves/block; online softmax.
__global__ __launch_bounds__(256) void k_attn(
    const bf16* __restrict__ qkv, const bf16* __restrict__ vT,
    const bf16* __restrict__ memkv, bf16* __restrict__ ctx, int layer) {
  const int bh = blockIdx.x;
  const int b = bh / H_, h = bh % H_;
  const int qt = (int)gridDim.y - 1 - (int)blockIdx.y;   // big q first
  const int tid = threadIdx.x;
  const int w = tid >> 6, l = tid & 63;
  const int lane15 = l & 15, lg = l >> 4;
  const float inv = 0.125f;

  __shared__ char plds[4][2048];     // per-wave P tile, 16 rows x 128B, XOR-swz
  __shared__ float wlp[4][16][16];   // per-wave memory logits
  char* pl = plds[w];

  const int qrow0 = qt * 64 + w * 16;
  const size_t rowA = (size_t)(b * S_ + qrow0 + lane15);
  const bf16* qp = qkv + rowA * 2304 + h * 64 + lg * 8;
  const bf16x8 qf0 = *(const bf16x8*)(qp);
  const bf16x8 qf1 = *(const bf16x8*)(qp + 32);

  const bf16* kbase = qkv + (size_t)(b * S_) * 2304 + 768 + h * 64 + lg * 8;
  const bf16* vbase = vT + ((size_t)(b * 768 + h * 64 + lane15)) * S_;

  float mrow[4], dsum[4];
  f32x4 acc[4];
#pragma unroll
  for (int j = 0; j < 4; j++) { mrow[j] = -INFINITY; dsum[j] = 0.f; }
#pragma unroll
  for (int ni = 0; ni < 4; ni++) acc[ni] = (f32x4){0.f, 0.f, 0.f, 0.f};

  const int ntile = ((qrow0 + 15) >> 6) + 1;
  for (int kt64 = 0; kt64 < ntile; kt64++) {
    const int k0 = kt64 * 64;
    f32x4 sc[4];
#pragma unroll
    for (int kt = 0; kt < 4; kt++) {
      const bf16* kp = kbase + (size_t)(k0 + kt * 16 + lane15) * 2304;
      bf16x8 kf0 = *(const bf16x8*)(kp);
      bf16x8 kf1 = *(const bf16x8*)(kp + 32);
      f32x4 z = (f32x4){0.f, 0.f, 0.f, 0.f};
      z = __builtin_amdgcn_mfma_f32_16x16x32_bf16(qf0, kf0, z, 0, 0, 0);
      sc[kt] = __builtin_amdgcn_mfma_f32_16x16x32_bf16(qf1, kf1, z, 0, 0, 0);
    }
    float tmax[4];
#pragma unroll
    for (int j = 0; j < 4; j++) tmax[j] = -INFINITY;
#pragma unroll
    for (int kt = 0; kt < 4; kt++) {
      const int kabs = k0 + kt * 16 + lane15;
#pragma unroll
      for (int j = 0; j < 4; j++) {
        const int qabs = qrow0 + lg * 4 + j;
        float v = (kabs <= qabs) ? sc[kt][j] * inv : -INFINITY;
        sc[kt][j] = v;
        tmax[j] = fmaxf(tmax[j], v);
      }
    }
#pragma unroll
    for (int off = 1; off < 16; off <<= 1)
#pragma unroll
      for (int j = 0; j < 4; j++) tmax[j] = fmaxf(tmax[j], __shfl_xor(tmax[j], off, 16));

    float psum[4];
#pragma unroll
    for (int j = 0; j < 4; j++) {
      const float mnew = fmaxf(mrow[j], tmax[j]);
      const float alpha = __expf(mrow[j] - mnew);
      mrow[j] = mnew;
      dsum[j] *= alpha;
#pragma unroll
      for (int ni = 0; ni < 4; ni++) acc[ni][j] *= alpha;
      psum[j] = 0.f;
    }
#pragma unroll
    for (int kt = 0; kt < 4; kt++) {
      const int gsl = kt * 2 + (lane15 >> 3);
      const int ebyte = (lane15 & 7) * 2;
#pragma unroll
      for (int j = 0; j < 4; j++) {
        const float p = __expf(sc[kt][j] - mrow[j]);
        psum[j] += p;
        const int r = lg * 4 + j;
        *(unsigned short*)(pl + r * 128 + ((gsl ^ (r & 7)) << 4) + ebyte) = f2bf(p);
      }
    }
#pragma unroll
    for (int off = 1; off < 16; off <<= 1)
#pragma unroll
      for (int j = 0; j < 4; j++) psum[j] += __shfl_xor(psum[j], off, 16);
#pragma unroll
    for (int j = 0; j < 4; j++) dsum[j] += psum[j];

#pragma unroll
    for (int ks = 0; ks < 2; ks++) {
      bf16x8 pa = *(const bf16x8*)(pl + lane15 * 128 +
                                   ((((ks << 2) + lg) ^ (lane15 & 7)) << 4));
      const bf16* vp = vbase + k0 + ks * 32 + lg * 8;
#pragma unroll
      for (int ni = 0; ni < 4; ni++) {
        bf16x8 vf = *(const bf16x8*)(vp + (size_t)ni * 16 * S_);
        acc[ni] = __builtin_amdgcn_mfma_f32_16x16x32_bf16(pa, vf, acc[ni], 0, 0, 0);
      }
    }
  }

  // ---- memory (per-position k_col/v_col of previous layers)
  const int r4 = lg * 4;
  if (lane15 < layer) {
    const int ml = lane15;
#pragma unroll
    for (int j = 0; j < 4; j++) {
      const size_t rowB = (size_t)(b * S_) + qrow0 + r4 + j;
      const bf16* qc = qkv + rowB * 2304 + 1536 + h * 64;
      const bf16* mk = memkv + ((size_t)ml * BS_ + rowB) * 1536 + h * 64;
      float d_ = 0.f;
#pragma unroll
      for (int t = 0; t < 8; t++) {
        bf16x8 qv = *(const bf16x8*)(qc + t * 8);
        bf16x8 kv = *(const bf16x8*)(mk + t * 8);
#pragma unroll
        for (int e = 0; e < 8; e++)
          d_ += bf2f((unsigned short)qv[e]) * bf2f((unsigned short)kv[e]);
      }
      wlp[w][r4 + j][ml] = d_ * inv;
    }
  }
  if (layer > 0) {
#pragma unroll
    for (int j = 0; j < 4; j++) {
      const int r = r4 + j;
      float mm = -INFINITY;
      for (int ml = 0; ml < layer; ml++) mm = fmaxf(mm, wlp[w][r][ml]);
      const float mnew = fmaxf(mrow[j], mm);
      const float alpha = __expf(mrow[j] - mnew);
      mrow[j] = mnew;
      dsum[j] *= alpha;
#pragma unroll
      for (int ni = 0; ni < 4; ni++) acc[ni][j] *= alpha;
      const size_t rowB = (size_t)(b * S_) + qrow0 + r;
      for (int ml = 0; ml < layer; ml++) {
        const float p = __expf(wlp[w][r][ml] - mnew);
        dsum[j] += p;
        const unsigned short* mv = (const unsigned short*)(memkv +
            ((size_t)ml * BS_ + rowB) * 1536 + 768 + h * 64 + lane15);
#pragma unroll
        for (int ni = 0; ni < 4; ni++)
          acc[ni][j] += p * bf2f(mv[ni * 16]);
      }
    }
  }

#pragma unroll
  for (int j = 0; j < 4; j++) {
    const float rd = 1.f / dsum[j];
    const size_t rowB = (size_t)(b * S_) + qrow0 + r4 + j;
    bf16* cp = ctx + rowB * 768 + h * 64 + lane15;
#pragma unroll
    for (int ni = 0; ni < 4; ni++)
      cp[ni * 16] = __float2bfloat16(acc[ni][j] * rd);
  }
}

// ---------------------------------------------------------------- launch
extern "C" void kernel_launch(void* const* d_in, const int* in_sizes, int n_in,
                              void* d_out, int out_size, void* d_ws, size_t ws_size,
                              hipStream_t stream) {
  const int*   tokens  = (const int*)d_in[0];
  const float* tok_emb = (const float*)d_in[1];
  const float* pos_emb = (const float*)d_in[2];
  const float *Wq_row, *Wk_row, *Wv_row, *Wq_col, *Wo;
  const float *bq_row, *bk_row, *bv_row, *bq_col, *bo;
  if (in_sizes[4] == L_ * D_ * D_) {  // dict order
    Wq_row = (const float*)d_in[3];  Wk_row = (const float*)d_in[4];
    Wv_row = (const float*)d_in[5];  Wq_col = (const float*)d_in[6];
    Wo     = (const float*)d_in[7];
    bq_row = (const float*)d_in[8];  bk_row = (const float*)d_in[9];
    bv_row = (const float*)d_in[10]; bq_col = (const float*)d_in[11];
    bo     = (const float*)d_in[12];
  } else {  // signature order fallback
    Wq_row = (const float*)d_in[3];  bq_row = (const float*)d_in[4];
    Wk_row = (const float*)d_in[5];  bk_row = (const float*)d_in[6];
    Wv_row = (const float*)d_in[7];  bv_row = (const float*)d_in[8];
    Wq_col = (const float*)d_in[9];  bq_col = (const float*)d_in[10];
    Wo     = (const float*)d_in[11]; bo     = (const float*)d_in[12];
  }
  const float* ln1_g = (const float*)d_in[13]; const float* ln1_b = (const float*)d_in[14];
  const float* ln2_g = (const float*)d_in[15]; const float* ln2_b = (const float*)d_in[16];
  const float* W1    = (const float*)d_in[17]; const float* b1    = (const float*)d_in[18];
  const float* W2    = (const float*)d_in[19]; const float* b2    = (const float*)d_in[20];
  const float* Wk_sh = (const float*)d_in[21]; const float* bk_sh = (const float*)d_in[22];
  const float* Wv_sh = (const float*)d_in[23]; const float* bv_sh = (const float*)d_in[24];
  const float* lnf_g = (const float*)d_in[25]; const float* lnf_b = (const float*)d_in[26];
  const float* Whead = (const float*)d_in[27]; const float* bhead = (const float*)d_in[28];

  // ---- workspace carve-up (all 16B-aligned sizes)
  char* p = (char*)d_ws;
  float* x      = (float*)p; p += (size_t)BS_ * D_ * 4;
  bf16*  h_bf   = (bf16*)p;  p += (size_t)BS_ * D_ * 2;
  bf16*  qkv3   = (bf16*)p;  p += (size_t)BS_ * 2304 * 2;
  bf16*  vTb    = (bf16*)p;  p += (size_t)B_ * 768 * S_ * 2;
  bf16*  memkv  = (bf16*)p;  p += (size_t)L_ * BS_ * 1536 * 2;
  bf16*  ctx_bf = (bf16*)p;  p += (size_t)BS_ * D_ * 2;
  bf16*  mlp_bf = (bf16*)p;  p += (size_t)BS_ * DFF_ * 2;
  float* b3cat  = (float*)p; p += (size_t)L_ * 2304 * 4;
  float* bshcat = (float*)p; p += (size_t)1536 * 4;
  bf16* tW3    = (bf16*)p; p += (size_t)L_ * 2304 * D_ * 2;
  bf16* tWv    = (bf16*)p; p += (size_t)L_ * D_ * D_ * 2;
  bf16* tWo    = (bf16*)p; p += (size_t)L_ * D_ * D_ * 2;
  bf16* tW1    = (bf16*)p; p += (size_t)L_ * DFF_ * D_ * 2;
  bf16* tW2    = (bf16*)p; p += (size_t)L_ * D_ * DFF_ * 2;
  bf16* tWsh   = (bf16*)p; p += (size_t)1536 * D_ * 2;
  bf16* tWhead = (bf16*)p; p += (size_t)V_ * D_ * 2;

  // ---- weight conversion (transposed bf16), bias concat
  dim3 tb(32, 8);
  const size_t DD = (size_t)D_ * D_;
  k_w2bf_t<<<dim3(24, 24, L_), tb, 0, stream>>>(Wq_row, tW3,             768, 768, DD, (size_t)2304 * 768);
  k_w2bf_t<<<dim3(24, 24, L_), tb, 0, stream>>>(Wk_row, tW3 + 768 * 768, 768, 768, DD, (size_t)2304 * 768);
  k_w2bf_t<<<dim3(24, 24, L_), tb, 0, stream>>>(Wq_col, tW3 + 1536 * 768, 768, 768, DD, (size_t)2304 * 768);
  k_w2bf_t<<<dim3(24, 24, L_), tb, 0, stream>>>(Wv_row, tWv, 768, 768, DD, DD);
  k_w2bf_t<<<dim3(24, 24, L_), tb, 0, stream>>>(Wo,     tWo, 768, 768, DD, DD);
  k_w2bf_t<<<dim3(96, 24, L_), tb, 0, stream>>>(W1, tW1, 768, 3072, (size_t)768 * 3072, (size_t)3072 * 768);
  k_w2bf_t<<<dim3(24, 96, L_), tb, 0, stream>>>(W2, tW2, 3072, 768, (size_t)768 * 3072, (size_t)768 * 3072);
  k_w2bf_t<<<dim3(24, 24, 1), tb, 0, stream>>>(Wk_sh, tWsh,             768, 768, 0, 0);
  k_w2bf_t<<<dim3(24, 24, 1), tb, 0, stream>>>(Wv_sh, tWsh + 768 * 768, 768, 768, 0, 0);
  k_w2bf_t<<<dim3(1000, 24, 1), tb, 0, stream>>>(Whead, tWhead, 768, 32000, 0, 0);
  k_bcat<<<dim3(72), 256, 0, stream>>>(bq_row, bk_row, bq_col, bk_sh, bv_sh, b3cat, bshcat);

  k_embed<<<dim3((BS_ * D_) / 256), 256, 0, stream>>>(tokens, tok_emb, pos_emb, x);

  for (int i = 0; i < L_; i++) {
    k_ln<<<dim3(BS_), 256, 0, stream>>>(x, ln1_g + i * D_, ln1_b + i * D_, h_bf);
    k_bgemm<128, 3><<<dim3(18, 16), 256, 0, stream>>>(
        h_bf, tW3 + (size_t)i * 2304 * 768, b3cat + (size_t)i * 2304,
        nullptr, nullptr, qkv3, BS_, 2304, 768);
    k_bgemm<64, 5><<<dim3(6, 32), 256, 0, stream>>>(
        h_bf, tWv + (size_t)i * DD, bv_row + i * D_, nullptr, nullptr, vTb,
        BS_, 768, 768);
    k_bgemm<64, 3><<<dim3(12, 32), 256, 0, stream>>>(
        h_bf, tWsh, bshcat, nullptr, nullptr, memkv + (size_t)i * BS_ * 1536,
        BS_, 1536, 768);
    k_attn<<<dim3(B_ * H_, S_ / 64), 256, 0, stream>>>(qkv3, vTb, memkv, ctx_bf, i);
    k_bgemm<64, 1><<<dim3(6, 32), 256, 0, stream>>>(
        ctx_bf, tWo + (size_t)i * DD, bo + i * D_, x, x, nullptr, BS_, 768, 768);
    k_ln<<<dim3(BS_), 256, 0, stream>>>(x, ln2_g + i * D_, ln2_b + i * D_, h_bf);
    k_bgemm<128, 2><<<dim3(24, 16), 256, 0, stream>>>(
        h_bf, tW1 + (size_t)i * 3072 * 768, b1 + (size_t)i * DFF_,
        nullptr, nullptr, mlp_bf, BS_, 3072, 768);
    k_bgemm<64, 1><<<dim3(6, 32), 256, 0, stream>>>(
        mlp_bf, tW2 + (size_t)i * 768 * 3072, b2 + i * D_, x, x, nullptr,
        BS_, 768, 3072);
  }
  k_ln<<<dim3(BS_), 256, 0, stream>>>(x, lnf_g, lnf_b, h_bf);
  k_bgemm<128, 0><<<dim3(250, 16), 256, 0, stream>>>(
      h_bf, tWhead, bhead, nullptr, (float*)d_out, nullptr, BS_, V_, 768);
}

// Round 4
// 2005.179 us; speedup vs baseline: 4.5811x; 1.1861x over previous
//
#include <hip/hip_runtime.h>
#include <hip/hip_bf16.h>
#include <math.h>

#define L_   8
#define D_   768
#define H_   12
#define V_   32000
#define B_   2
#define S_   1024
#define HD_  64
#define BS_  2048      // B_*S_
#define DFF_ 3072      // MR*D

typedef __hip_bfloat16 bf16;
typedef __attribute__((ext_vector_type(8))) short bf16x8;
typedef __attribute__((ext_vector_type(4))) float f32x4;

#define CFUN(r) ((((r) & 3)) ^ (((r) >> 2) & 3))

__device__ __forceinline__ void cp16(void* lds, const void* g) {
  __builtin_amdgcn_global_load_lds(
      (const __attribute__((address_space(1))) void*)g,
      (__attribute__((address_space(3))) void*)lds, 16, 0, 0);
}

__device__ __forceinline__ unsigned short f2bf(float v) {
  __hip_bfloat16 h = __float2bfloat16(v);
  return *reinterpret_cast<unsigned short*>(&h);
}
__device__ __forceinline__ float bf2f(unsigned short u) {
  return __uint_as_float(((unsigned)u) << 16);
}

// ---------------------------------------------------------------- embedding
__global__ __launch_bounds__(256) void k_embed(const int* __restrict__ tokens,
    const float* __restrict__ tok_emb, const float* __restrict__ pos_emb,
    float* __restrict__ x) {
  int idx = blockIdx.x * 256 + threadIdx.x;
  int row = idx / D_;
  int d   = idx - row * D_;
  int s   = row & (S_ - 1);
  int t   = tokens[row];
  x[idx] = tok_emb[(size_t)t * D_ + d] + pos_emb[(size_t)s * D_ + d];
}

// ---------------------------------------------------------------- layernorm -> bf16
__global__ __launch_bounds__(256) void k_ln(const float* __restrict__ x,
    const float* __restrict__ g, const float* __restrict__ b,
    bf16* __restrict__ out) {
  int row = blockIdx.x;
  const float* xr = x + (size_t)row * D_;
  int t = threadIdx.x;
  float v0 = xr[t], v1 = xr[t + 256], v2 = xr[t + 512];
  float s  = v0 + v1 + v2;
  float s2 = v0 * v0 + v1 * v1 + v2 * v2;
#pragma unroll
  for (int off = 32; off; off >>= 1) {
    s  += __shfl_down(s, off);
    s2 += __shfl_down(s2, off);
  }
  __shared__ float rs[4], rs2[4];
  __shared__ float mean_s, rstd_s;
  int wid = t >> 6;
  if ((t & 63) == 0) { rs[wid] = s; rs2[wid] = s2; }
  __syncthreads();
  if (t == 0) {
    float S1 = rs[0] + rs[1] + rs[2] + rs[3];
    float S2 = rs2[0] + rs2[1] + rs2[2] + rs2[3];
    float m  = S1 / D_;
    float var = S2 / D_ - m * m;
    mean_s = m;
    rstd_s = rsqrtf(var + 1e-5f);
  }
  __syncthreads();
  float m = mean_s, r = rstd_s;
  bf16* orow = out + (size_t)row * D_;
  orow[t]       = __float2bfloat16((v0 - m) * r * g[t]       + b[t]);
  orow[t + 256] = __float2bfloat16((v1 - m) * r * g[t + 256] + b[t + 256]);
  orow[t + 512] = __float2bfloat16((v2 - m) * r * g[t + 512] + b[t + 512]);
}

// ------------------------------------------------- weight convert + transpose
// W[K][N] f32 -> Wt[N][K] bf16 (slice-capable). grid (N/32, K/32, nz).
__global__ __launch_bounds__(256) void k_w2bf_t(const float* __restrict__ W,
    bf16* __restrict__ Wt, int K, int N, size_t ils, size_t ols) {
  __shared__ float t[32][33];
  const float* Wm = W + (size_t)blockIdx.z * ils;
  bf16* Wtm = Wt + (size_t)blockIdx.z * ols;
  int n0 = blockIdx.x * 32, k0 = blockIdx.y * 32;
  int tx = threadIdx.x;
  for (int i = threadIdx.y; i < 32; i += 8)
    t[i][tx] = Wm[(size_t)(k0 + i) * N + n0 + tx];
  __syncthreads();
  for (int i = threadIdx.y; i < 32; i += 8)
    Wtm[(size_t)(n0 + i) * K + k0 + tx] = __float2bfloat16(t[tx][i]);
}

// ---------------------------------------------------------------- bias concat
// b4cat[L][3072] = bq|bk|bqc|bv ; bshcat[1536] = bksh|bvsh
__global__ __launch_bounds__(256) void k_bcat(const float* __restrict__ bq,
    const float* __restrict__ bk, const float* __restrict__ bqc,
    const float* __restrict__ bv, const float* __restrict__ bksh,
    const float* __restrict__ bvsh, float* __restrict__ b4,
    float* __restrict__ bsh) {
  int idx = blockIdx.x * 256 + threadIdx.x;
  if (idx < L_ * 3072) {
    int l = idx / 3072, c = idx - l * 3072;
    float v = (c < 768)  ? bq[l * 768 + c]
            : (c < 1536) ? bk[l * 768 + c - 768]
            : (c < 2304) ? bqc[l * 768 + c - 1536]
                         : bv[l * 768 + c - 2304];
    b4[idx] = v;
  }
  if (idx < 1536) bsh[idx] = (idx < 768) ? bksh[idx] : bvsh[idx - 768];
}

// ---------------------------------------------------------------- bf16 MFMA GEMM
// C[M,N] = A[M,K](bf16) @ Wt[N,K](bf16)^T + bias. BMx128 tile, BK=32, 4 waves,
// double-buffered LDS: stage(t+1) issued before compute(t), 1 barrier/K-step.
// EPI: 0 f32+bias; 1 f32+bias+resid; 2 bf16+bias+gelu; 3 bf16+bias;
//      6 fused qkv|v routing (col<2304 -> Cb[row*2304+col], else vT transposed)
template <int BM, int EPI, bool MSWAP>
__global__ __launch_bounds__(256) void k_bgemm(
    const bf16* __restrict__ A, const bf16* __restrict__ Wt,
    const float* __restrict__ bias, const float* __restrict__ resid,
    float* __restrict__ Cf, bf16* __restrict__ Cb, bf16* __restrict__ Cb2,
    int M, int N, int K) {
  constexpr int ASZ = BM * 64;           // bytes per A buffer
  constexpr int MF = BM / 32;
  __shared__ __align__(16) char smem[2 * ASZ + 16384];
  const int tid = threadIdx.x;
  const int l = tid & 63, w = tid >> 6;
  const int wr = w >> 1, wc = w & 1;
  const int m0 = (MSWAP ? blockIdx.x : blockIdx.y) * BM;
  const int n0 = (MSWAP ? blockIdx.y : blockIdx.x) * 128;
  const int lane15 = l & 15, lg = l >> 4;

  const int r0 = tid >> 2, p0 = tid & 3;
  const int r1 = 64 + r0;
  const char* aSrc0 = (const char*)(A  + (size_t)(m0 + r0) * K) + ((p0 ^ CFUN(r0)) * 16);
  const char* aSrc1 = (const char*)(A  + (size_t)(m0 + r1) * K) + ((p0 ^ CFUN(r1)) * 16);
  const char* bSrc0 = (const char*)(Wt + (size_t)(n0 + r0) * K) + ((p0 ^ CFUN(r0)) * 16);
  const char* bSrc1 = (const char*)(Wt + (size_t)(n0 + r1) * K) + ((p0 ^ CFUN(r1)) * 16);

  int aOff[MF], bOff[4];
#pragma unroll
  for (int mi = 0; mi < MF; mi++) {
    int r = wr * (BM / 2) + mi * 16 + lane15;
    aOff[mi] = r * 64 + ((lg ^ CFUN(r)) * 16);
  }
#pragma unroll
  for (int ni = 0; ni < 4; ni++) {
    int r = wc * 64 + ni * 16 + lane15;
    bOff[ni] = r * 64 + ((lg ^ CFUN(r)) * 16);
  }

  f32x4 acc[MF][4];
#pragma unroll
  for (int mi = 0; mi < MF; mi++)
#pragma unroll
    for (int ni = 0; ni < 4; ni++) acc[mi][ni] = (f32x4){0.f, 0.f, 0.f, 0.f};

  auto stage = [&](int buf, int t) {
    const size_t kb = (size_t)t * 64;
    cp16(smem + buf * ASZ + w * 1024, aSrc0 + kb);
    if constexpr (BM == 128) cp16(smem + buf * ASZ + 4096 + w * 1024, aSrc1 + kb);
    cp16(smem + 2 * ASZ + buf * 8192 + w * 1024, bSrc0 + kb);
    cp16(smem + 2 * ASZ + buf * 8192 + 4096 + w * 1024, bSrc1 + kb);
  };
  auto compute = [&](int buf) {
    const char* ab = smem + buf * ASZ;
    const char* bb = smem + 2 * ASZ + buf * 8192;
    bf16x8 af[MF], bfr[4];
#pragma unroll
    for (int mi = 0; mi < MF; mi++) af[mi] = *(const bf16x8*)(ab + aOff[mi]);
#pragma unroll
    for (int ni = 0; ni < 4; ni++) bfr[ni] = *(const bf16x8*)(bb + bOff[ni]);
#pragma unroll
    for (int mi = 0; mi < MF; mi++)
#pragma unroll
      for (int ni = 0; ni < 4; ni++)
        acc[mi][ni] = __builtin_amdgcn_mfma_f32_16x16x32_bf16(
            af[mi], bfr[ni], acc[mi][ni], 0, 0, 0);
  };

  const int nk = K >> 5;                 // always even (24 or 96)
  stage(0, 0);
  __syncthreads();
  for (int t = 0; t < nk; t += 2) {
    if (t + 1 < nk) stage(1, t + 1);
    compute(0);
    __syncthreads();
    if (t + 2 < nk) stage(0, t + 2);
    compute(1);
    __syncthreads();
  }

#pragma unroll
  for (int ni = 0; ni < 4; ni++) {
    const int col = n0 + wc * 64 + ni * 16 + lane15;
    const float bv = bias[col];
#pragma unroll
    for (int mi = 0; mi < MF; mi++) {
      const int rowb = m0 + wr * (BM / 2) + mi * 16 + lg * 4;
      if constexpr (EPI == 6) {
        if (col < 2304) {
#pragma unroll
          for (int j = 0; j < 4; j++)
            Cb[(size_t)(rowb + j) * 2304 + col] = __float2bfloat16(acc[mi][ni][j] + bv);
        } else {
          ushort4 pk;
          pk.x = f2bf(acc[mi][ni][0] + bv);
          pk.y = f2bf(acc[mi][ni][1] + bv);
          pk.z = f2bf(acc[mi][ni][2] + bv);
          pk.w = f2bf(acc[mi][ni][3] + bv);
          const int bq = rowb >> 10, s = rowb & (S_ - 1);
          *reinterpret_cast<ushort4*>(
              (unsigned short*)Cb2 + ((size_t)(bq * 768 + (col - 2304))) * S_ + s) = pk;
        }
      } else {
#pragma unroll
        for (int j = 0; j < 4; j++) {
          const int row = rowb + j;
          float v = acc[mi][ni][j] + bv;
          if constexpr (EPI == 1) v += resid[(size_t)row * N + col];
          if constexpr (EPI == 2) {
            v = 0.5f * v * (1.0f + erff(v * 0.70710678118654752f));
            Cb[(size_t)row * N + col] = __float2bfloat16(v);
          } else if constexpr (EPI == 3) {
            Cb[(size_t)row * N + col] = __float2bfloat16(v);
          } else {
            Cf[(size_t)row * N + col] = v;
          }
        }
      }
    }
  }
}

// ---------------------------------------------------------------- flash attention
// qkv [BS][2304] = q|k|qc (bf16). vT [B*768][S] bf16. memkv [L][BS][1536] = ksh|vsh.
__global__ __launch_bounds__(256) void k_attn(
    const bf16* __restrict__ qkv, const bf16* __restrict__ vT,
    const bf16* __restrict__ memkv, bf16* __restrict__ ctx, int layer) {
  const int bh = blockIdx.x;
  const int b = bh / H_, h = bh % H_;
  const int qt = (int)gridDim.y - 1 - (int)blockIdx.y;   // big q first
  const int tid = threadIdx.x;
  const int w = tid >> 6, l = tid & 63;
  const int lane15 = l & 15, lg = l >> 4;
  const float inv = 0.125f;

  __shared__ char plds[4][2048];     // per-wave P tile, 16 rows x 128B, XOR-swz
  __shared__ float wlp[4][16][16];   // per-wave memory logits
  char* pl = plds[w];

  const int qrow0 = qt * 64 + w * 16;
  const size_t rowA = (size_t)(b * S_ + qrow0 + lane15);
  const bf16* qp = qkv + rowA * 2304 + h * 64 + lg * 8;
  const bf16x8 qf0 = *(const bf16x8*)(qp);
  const bf16x8 qf1 = *(const bf16x8*)(qp + 32);

  const bf16* kbase = qkv + (size_t)(b * S_) * 2304 + 768 + h * 64 + lg * 8;
  const bf16* vbase = vT + ((size_t)(b * 768 + h * 64 + lane15)) * S_;

  float mrow[4], dsum[4];
  f32x4 acc[4];
#pragma unroll
  for (int j = 0; j < 4; j++) { mrow[j] = -INFINITY; dsum[j] = 0.f; }
#pragma unroll
  for (int ni = 0; ni < 4; ni++) acc[ni] = (f32x4){0.f, 0.f, 0.f, 0.f};

  const int ntile = ((qrow0 + 15) >> 6) + 1;
  for (int kt64 = 0; kt64 < ntile; kt64++) {
    const int k0 = kt64 * 64;
    f32x4 sc[4];
#pragma unroll
    for (int kt = 0; kt < 4; kt++) {
      const bf16* kp = kbase + (size_t)(k0 + kt * 16 + lane15) * 2304;
      bf16x8 kf0 = *(const bf16x8*)(kp);
      bf16x8 kf1 = *(const bf16x8*)(kp + 32);
      f32x4 z = (f32x4){0.f, 0.f, 0.f, 0.f};
      z = __builtin_amdgcn_mfma_f32_16x16x32_bf16(qf0, kf0, z, 0, 0, 0);
      sc[kt] = __builtin_amdgcn_mfma_f32_16x16x32_bf16(qf1, kf1, z, 0, 0, 0);
    }
    float tmax[4];
#pragma unroll
    for (int j = 0; j < 4; j++) tmax[j] = -INFINITY;
#pragma unroll
    for (int kt = 0; kt < 4; kt++) {
      const int kabs = k0 + kt * 16 + lane15;
#pragma unroll
      for (int j = 0; j < 4; j++) {
        const int qabs = qrow0 + lg * 4 + j;
        float v = (kabs <= qabs) ? sc[kt][j] * inv : -INFINITY;
        sc[kt][j] = v;
        tmax[j] = fmaxf(tmax[j], v);
      }
    }
#pragma unroll
    for (int off = 1; off < 16; off <<= 1)
#pragma unroll
      for (int j = 0; j < 4; j++) tmax[j] = fmaxf(tmax[j], __shfl_xor(tmax[j], off, 16));

    float psum[4];
#pragma unroll
    for (int j = 0; j < 4; j++) {
      const float mnew = fmaxf(mrow[j], tmax[j]);
      const float alpha = __expf(mrow[j] - mnew);
      mrow[j] = mnew;
      dsum[j] *= alpha;
#pragma unroll
      for (int ni = 0; ni < 4; ni++) acc[ni][j] *= alpha;
      psum[j] = 0.f;
    }
#pragma unroll
    for (int kt = 0; kt < 4; kt++) {
      const int gsl = kt * 2 + (lane15 >> 3);
      const int ebyte = (lane15 & 7) * 2;
#pragma unroll
      for (int j = 0; j < 4; j++) {
        const float p = __expf(sc[kt][j] - mrow[j]);
        psum[j] += p;
        const int r = lg * 4 + j;
        *(unsigned short*)(pl + r * 128 + ((gsl ^ (r & 7)) << 4) + ebyte) = f2bf(p);
      }
    }
#pragma unroll
    for (int off = 1; off < 16; off <<= 1)
#pragma unroll
      for (int j = 0; j < 4; j++) psum[j] += __shfl_xor(psum[j], off, 16);
#pragma unroll
    for (int j = 0; j < 4; j++) dsum[j] += psum[j];

#pragma unroll
    for (int ks = 0; ks < 2; ks++) {
      bf16x8 pa = *(const bf16x8*)(pl + lane15 * 128 +
                                   ((((ks << 2) + lg) ^ (lane15 & 7)) << 4));
      const bf16* vp = vbase + k0 + ks * 32 + lg * 8;
#pragma unroll
      for (int ni = 0; ni < 4; ni++) {
        bf16x8 vf = *(const bf16x8*)(vp + (size_t)ni * 16 * S_);
        acc[ni] = __builtin_amdgcn_mfma_f32_16x16x32_bf16(pa, vf, acc[ni], 0, 0, 0);
      }
    }
  }

  // ---- memory (per-position k_col/v_col of previous layers)
  const int r4 = lg * 4;
  if (lane15 < layer) {
    const int ml = lane15;
#pragma unroll
    for (int j = 0; j < 4; j++) {
      const size_t rowB = (size_t)(b * S_) + qrow0 + r4 + j;
      const bf16* qc = qkv + rowB * 2304 + 1536 + h * 64;
      const bf16* mk = memkv + ((size_t)ml * BS_ + rowB) * 1536 + h * 64;
      float d_ = 0.f;
#pragma unroll
      for (int t = 0; t < 8; t++) {
        bf16x8 qv = *(const bf16x8*)(qc + t * 8);
        bf16x8 kv = *(const bf16x8*)(mk + t * 8);
#pragma unroll
        for (int e = 0; e < 8; e++)
          d_ += bf2f((unsigned short)qv[e]) * bf2f((unsigned short)kv[e]);
      }
      wlp[w][r4 + j][ml] = d_ * inv;
    }
  }
  if (layer > 0) {
#pragma unroll
    for (int j = 0; j < 4; j++) {
      const int r = r4 + j;
      float mm = -INFINITY;
      for (int ml = 0; ml < layer; ml++) mm = fmaxf(mm, wlp[w][r][ml]);
      const float mnew = fmaxf(mrow[j], mm);
      const float alpha = __expf(mrow[j] - mnew);
      mrow[j] = mnew;
      dsum[j] *= alpha;
#pragma unroll
      for (int ni = 0; ni < 4; ni++) acc[ni][j] *= alpha;
      const size_t rowB = (size_t)(b * S_) + qrow0 + r;
      for (int ml = 0; ml < layer; ml++) {
        const float p = __expf(wlp[w][r][ml] - mnew);
        dsum[j] += p;
        const unsigned short* mv = (const unsigned short*)(memkv +
            ((size_t)ml * BS_ + rowB) * 1536 + 768 + h * 64 + lane15);
#pragma unroll
        for (int ni = 0; ni < 4; ni++)
          acc[ni][j] += p * bf2f(mv[ni * 16]);
      }
    }
  }

#pragma unroll
  for (int j = 0; j < 4; j++) {
    const float rd = 1.f / dsum[j];
    const size_t rowB = (size_t)(b * S_) + qrow0 + r4 + j;
    bf16* cp = ctx + rowB * 768 + h * 64 + lane15;
#pragma unroll
    for (int ni = 0; ni < 4; ni++)
      cp[ni * 16] = __float2bfloat16(acc[ni][j] * rd);
  }
}

// ---------------------------------------------------------------- launch
extern "C" void kernel_launch(void* const* d_in, const int* in_sizes, int n_in,
                              void* d_out, int out_size, void* d_ws, size_t ws_size,
                              hipStream_t stream) {
  const int*   tokens  = (const int*)d_in[0];
  const float* tok_emb = (const float*)d_in[1];
  const float* pos_emb = (const float*)d_in[2];
  const float *Wq_row, *Wk_row, *Wv_row, *Wq_col, *Wo;
  const float *bq_row, *bk_row, *bv_row, *bq_col, *bo;
  if (in_sizes[4] == L_ * D_ * D_) {  // dict order
    Wq_row = (const float*)d_in[3];  Wk_row = (const float*)d_in[4];
    Wv_row = (const float*)d_in[5];  Wq_col = (const float*)d_in[6];
    Wo     = (const float*)d_in[7];
    bq_row = (const float*)d_in[8];  bk_row = (const float*)d_in[9];
    bv_row = (const float*)d_in[10]; bq_col = (const float*)d_in[11];
    bo     = (const float*)d_in[12];
  } else {  // signature order fallback
    Wq_row = (const float*)d_in[3];  bq_row = (const float*)d_in[4];
    Wk_row = (const float*)d_in[5];  bk_row = (const float*)d_in[6];
    Wv_row = (const float*)d_in[7];  bv_row = (const float*)d_in[8];
    Wq_col = (const float*)d_in[9];  bq_col = (const float*)d_in[10];
    Wo     = (const float*)d_in[11]; bo     = (const float*)d_in[12];
  }
  const float* ln1_g = (const float*)d_in[13]; const float* ln1_b = (const float*)d_in[14];
  const float* ln2_g = (const float*)d_in[15]; const float* ln2_b = (const float*)d_in[16];
  const float* W1    = (const float*)d_in[17]; const float* b1    = (const float*)d_in[18];
  const float* W2    = (const float*)d_in[19]; const float* b2    = (const float*)d_in[20];
  const float* Wk_sh = (const float*)d_in[21]; const float* bk_sh = (const float*)d_in[22];
  const float* Wv_sh = (const float*)d_in[23]; const float* bv_sh = (const float*)d_in[24];
  const float* lnf_g = (const float*)d_in[25]; const float* lnf_b = (const float*)d_in[26];
  const float* Whead = (const float*)d_in[27]; const float* bhead = (const float*)d_in[28];

  // ---- workspace carve-up
  char* p = (char*)d_ws;
  float* x      = (float*)p; p += (size_t)BS_ * D_ * 4;
  bf16*  h_bf   = (bf16*)p;  p += (size_t)BS_ * D_ * 2;
  bf16*  qkv3   = (bf16*)p;  p += (size_t)BS_ * 2304 * 2;
  bf16*  vTb    = (bf16*)p;  p += (size_t)B_ * 768 * S_ * 2;
  bf16*  memkv  = (bf16*)p;  p += (size_t)L_ * BS_ * 1536 * 2;
  bf16*  ctx_bf = (bf16*)p;  p += (size_t)BS_ * D_ * 2;
  bf16*  mlp_bf = (bf16*)p;  p += (size_t)BS_ * DFF_ * 2;
  float* b4cat  = (float*)p; p += (size_t)L_ * 3072 * 4;
  float* bshcat = (float*)p; p += (size_t)1536 * 4;
  bf16* tW4    = (bf16*)p; p += (size_t)L_ * 3072 * D_ * 2;   // q|k|qc|v rows
  bf16* tWo    = (bf16*)p; p += (size_t)L_ * D_ * D_ * 2;
  bf16* tW1    = (bf16*)p; p += (size_t)L_ * DFF_ * D_ * 2;
  bf16* tW2    = (bf16*)p; p += (size_t)L_ * D_ * DFF_ * 2;
  bf16* tWsh   = (bf16*)p; p += (size_t)1536 * D_ * 2;
  bf16* tWhead = (bf16*)p; p += (size_t)V_ * D_ * 2;

  // ---- weight conversion (transposed bf16), bias concat
  dim3 tb(32, 8);
  const size_t DD = (size_t)D_ * D_;
  const size_t W4S = (size_t)3072 * 768;
  k_w2bf_t<<<dim3(24, 24, L_), tb, 0, stream>>>(Wq_row, tW4,               768, 768, DD, W4S);
  k_w2bf_t<<<dim3(24, 24, L_), tb, 0, stream>>>(Wk_row, tW4 + 768 * 768,   768, 768, DD, W4S);
  k_w2bf_t<<<dim3(24, 24, L_), tb, 0, stream>>>(Wq_col, tW4 + 1536 * 768,  768, 768, DD, W4S);
  k_w2bf_t<<<dim3(24, 24, L_), tb, 0, stream>>>(Wv_row, tW4 + 2304 * 768,  768, 768, DD, W4S);
  k_w2bf_t<<<dim3(24, 24, L_), tb, 0, stream>>>(Wo,     tWo, 768, 768, DD, DD);
  k_w2bf_t<<<dim3(96, 24, L_), tb, 0, stream>>>(W1, tW1, 768, 3072, (size_t)768 * 3072, (size_t)3072 * 768);
  k_w2bf_t<<<dim3(24, 96, L_), tb, 0, stream>>>(W2, tW2, 3072, 768, (size_t)768 * 3072, (size_t)768 * 3072);
  k_w2bf_t<<<dim3(24, 24, 1), tb, 0, stream>>>(Wk_sh, tWsh,             768, 768, 0, 0);
  k_w2bf_t<<<dim3(24, 24, 1), tb, 0, stream>>>(Wv_sh, tWsh + 768 * 768, 768, 768, 0, 0);
  k_w2bf_t<<<dim3(1000, 24, 1), tb, 0, stream>>>(Whead, tWhead, 768, 32000, 0, 0);
  k_bcat<<<dim3(96), 256, 0, stream>>>(bq_row, bk_row, bq_col, bv_row, bk_sh, bv_sh,
                                       b4cat, bshcat);

  k_embed<<<dim3((BS_ * D_) / 256), 256, 0, stream>>>(tokens, tok_emb, pos_emb, x);

  for (int i = 0; i < L_; i++) {
    k_ln<<<dim3(BS_), 256, 0, stream>>>(x, ln1_g + i * D_, ln1_b + i * D_, h_bf);
    k_bgemm<128, 6, false><<<dim3(24, 16), 256, 0, stream>>>(
        h_bf, tW4 + (size_t)i * W4S, b4cat + (size_t)i * 3072,
        nullptr, nullptr, qkv3, vTb, BS_, 3072, 768);
    k_bgemm<64, 3, false><<<dim3(12, 32), 256, 0, stream>>>(
        h_bf, tWsh, bshcat, nullptr, nullptr, memkv + (size_t)i * BS_ * 1536,
        nullptr, BS_, 1536, 768);
    k_attn<<<dim3(B_ * H_, S_ / 64), 256, 0, stream>>>(qkv3, vTb, memkv, ctx_bf, i);
    k_bgemm<64, 1, false><<<dim3(6, 32), 256, 0, stream>>>(
        ctx_bf, tWo + (size_t)i * DD, bo + i * D_, x, x, nullptr, nullptr,
        BS_, 768, 768);
    k_ln<<<dim3(BS_), 256, 0, stream>>>(x, ln2_g + i * D_, ln2_b + i * D_, h_bf);
    k_bgemm<128, 2, false><<<dim3(24, 16), 256, 0, stream>>>(
        h_bf, tW1 + (size_t)i * 3072 * 768, b1 + (size_t)i * DFF_,
        nullptr, nullptr, mlp_bf, nullptr, BS_, 3072, 768);
    k_bgemm<64, 1, false><<<dim3(6, 32), 256, 0, stream>>>(
        mlp_bf, tW2 + (size_t)i * 768 * 3072, b2 + i * D_, x, x, nullptr,
        nullptr, BS_, 768, 3072);
  }
  k_ln<<<dim3(BS_), 256, 0, stream>>>(x, lnf_g, lnf_b, h_bf);
  k_bgemm<128, 0, true><<<dim3(16, 250), 256, 0, stream>>>(
      h_bf, tWhead, bhead, nullptr, (float*)d_out, nullptr, nullptr,
      BS_, V_, 768);
}

// Round 5
// 1989.298 us; speedup vs baseline: 4.6177x; 1.0080x over previous
//
#include <hip/hip_runtime.h>
#include <hip/hip_bf16.h>
#include <math.h>

#define L_   8
#define D_   768
#define H_   12
#define V_   32000
#define B_   2
#define S_   1024
#define HD_  64
#define BS_  2048      // B_*S_
#define DFF_ 3072      // MR*D

typedef __hip_bfloat16 bf16;
typedef __attribute__((ext_vector_type(8))) short bf16x8;
typedef __attribute__((ext_vector_type(4))) float f32x4;

#define CFUN(r) ((((r) & 3)) ^ (((r) >> 2) & 3))

__device__ __forceinline__ void cp16(void* lds, const void* g) {
  __builtin_amdgcn_global_load_lds(
      (const __attribute__((address_space(1))) void*)g,
      (__attribute__((address_space(3))) void*)lds, 16, 0, 0);
}

__device__ __forceinline__ unsigned short f2bf(float v) {
  __hip_bfloat16 h = __float2bfloat16(v);
  return *reinterpret_cast<unsigned short*>(&h);
}
__device__ __forceinline__ float bf2f(unsigned short u) {
  return __uint_as_float(((unsigned)u) << 16);
}

// ---------------------------------------------------------------- embedding
__global__ __launch_bounds__(256) void k_embed(const int* __restrict__ tokens,
    const float* __restrict__ tok_emb, const float* __restrict__ pos_emb,
    float* __restrict__ x) {
  int idx = blockIdx.x * 256 + threadIdx.x;
  int row = idx / D_;
  int d   = idx - row * D_;
  int s   = row & (S_ - 1);
  int t   = tokens[row];
  x[idx] = tok_emb[(size_t)t * D_ + d] + pos_emb[(size_t)s * D_ + d];
}

// ---------------------------------------------------------------- layernorm -> bf16
__global__ __launch_bounds__(256) void k_ln(const float* __restrict__ x,
    const float* __restrict__ g, const float* __restrict__ b,
    bf16* __restrict__ out) {
  int row = blockIdx.x;
  const float* xr = x + (size_t)row * D_;
  int t = threadIdx.x;
  float v0 = xr[t], v1 = xr[t + 256], v2 = xr[t + 512];
  float s  = v0 + v1 + v2;
  float s2 = v0 * v0 + v1 * v1 + v2 * v2;
#pragma unroll
  for (int off = 32; off; off >>= 1) {
    s  += __shfl_down(s, off);
    s2 += __shfl_down(s2, off);
  }
  __shared__ float rs[4], rs2[4];
  __shared__ float mean_s, rstd_s;
  int wid = t >> 6;
  if ((t & 63) == 0) { rs[wid] = s; rs2[wid] = s2; }
  __syncthreads();
  if (t == 0) {
    float S1 = rs[0] + rs[1] + rs[2] + rs[3];
    float S2 = rs2[0] + rs2[1] + rs2[2] + rs2[3];
    float m  = S1 / D_;
    float var = S2 / D_ - m * m;
    mean_s = m;
    rstd_s = rsqrtf(var + 1e-5f);
  }
  __syncthreads();
  float m = mean_s, r = rstd_s;
  bf16* orow = out + (size_t)row * D_;
  orow[t]       = __float2bfloat16((v0 - m) * r * g[t]       + b[t]);
  orow[t + 256] = __float2bfloat16((v1 - m) * r * g[t + 256] + b[t + 256]);
  orow[t + 512] = __float2bfloat16((v2 - m) * r * g[t + 512] + b[t + 512]);
}

// ------------------------------------------------- weight convert + transpose
// W[K][N] f32 -> Wt[N][K] bf16 (slice-capable). grid (N/32, K/32, nz).
// ils==0 replicates the same source into every z slice.
__global__ __launch_bounds__(256) void k_w2bf_t(const float* __restrict__ W,
    bf16* __restrict__ Wt, int K, int N, size_t ils, size_t ols) {
  __shared__ float t[32][33];
  const float* Wm = W + (size_t)blockIdx.z * ils;
  bf16* Wtm = Wt + (size_t)blockIdx.z * ols;
  int n0 = blockIdx.x * 32, k0 = blockIdx.y * 32;
  int tx = threadIdx.x;
  for (int i = threadIdx.y; i < 32; i += 8)
    t[i][tx] = Wm[(size_t)(k0 + i) * N + n0 + tx];
  __syncthreads();
  for (int i = threadIdx.y; i < 32; i += 8)
    Wtm[(size_t)(n0 + i) * K + k0 + tx] = __float2bfloat16(t[tx][i]);
}

// ---------------------------------------------------------------- bias concat
// b6cat[L][4608] = bq|bk|bqc|bv|bksh|bvsh
__global__ __launch_bounds__(256) void k_bcat(const float* __restrict__ bq,
    const float* __restrict__ bk, const float* __restrict__ bqc,
    const float* __restrict__ bv, const float* __restrict__ bksh,
    const float* __restrict__ bvsh, float* __restrict__ b6) {
  int idx = blockIdx.x * 256 + threadIdx.x;
  if (idx >= L_ * 4608) return;
  int l = idx / 4608, c = idx - l * 4608;
  float v = (c < 768)  ? bq[l * 768 + c]
          : (c < 1536) ? bk[l * 768 + c - 768]
          : (c < 2304) ? bqc[l * 768 + c - 1536]
          : (c < 3072) ? bv[l * 768 + c - 2304]
          : (c < 3840) ? bksh[c - 3072]
                       : bvsh[c - 3840];
  b6[idx] = v;
}

// ---------------------------------------------------------------- bf16 MFMA GEMM
// C[M,N] = A[M,K](bf16) @ Wt[N,K](bf16)^T + bias. BMx128 tile, BK=32, 4 waves,
// double-buffered LDS, 1-D grid with chunked XCD remap (m-fast decode: blocks
// on one XCD share W panels -> W lives in exactly one per-XCD L2).
// EPI: 0 f32+bias; 1 f32+bias+resid; 2 bf16+bias+gelu; 3 bf16+bias;
//      6 fused routing: col<2304 -> qkv [row][2304]; <3072 -> vT transposed;
//        else -> memkv [row][1536].
template <int BM, int EPI>
__global__ __launch_bounds__(256) void k_bgemm(
    const bf16* __restrict__ A, const bf16* __restrict__ Wt,
    const float* __restrict__ bias, const float* __restrict__ resid,
    float* __restrict__ Cf, bf16* __restrict__ Cb, bf16* __restrict__ Cb2,
    bf16* __restrict__ Cb3, int NM, int M, int N, int K) {
  constexpr int ASZ = BM * 64;           // bytes per A buffer
  constexpr int MF = BM / 32;
  __shared__ __align__(16) char smem[2 * ASZ + 16384];
  const int tid = threadIdx.x;
  const int l = tid & 63, w = tid >> 6;
  const int wr = w >> 1, wc = w & 1;

  // chunked XCD remap (nwg % 8 == 0), then m-fast decode
  const int nwg = (int)gridDim.x;
  int id = (int)blockIdx.x;
  id = (id & 7) * (nwg >> 3) + (id >> 3);
  const int m0 = (id % NM) * BM;
  const int n0 = (id / NM) * 128;

  const int lane15 = l & 15, lg = l >> 4;

  const int r0 = tid >> 2, p0 = tid & 3;
  const int r1 = 64 + r0;
  const char* aSrc0 = (const char*)(A  + (size_t)(m0 + r0) * K) + ((p0 ^ CFUN(r0)) * 16);
  const char* aSrc1 = (const char*)(A  + (size_t)(m0 + r1) * K) + ((p0 ^ CFUN(r1)) * 16);
  const char* bSrc0 = (const char*)(Wt + (size_t)(n0 + r0) * K) + ((p0 ^ CFUN(r0)) * 16);
  const char* bSrc1 = (const char*)(Wt + (size_t)(n0 + r1) * K) + ((p0 ^ CFUN(r1)) * 16);

  int aOff[MF], bOff[4];
#pragma unroll
  for (int mi = 0; mi < MF; mi++) {
    int r = wr * (BM / 2) + mi * 16 + lane15;
    aOff[mi] = r * 64 + ((lg ^ CFUN(r)) * 16);
  }
#pragma unroll
  for (int ni = 0; ni < 4; ni++) {
    int r = wc * 64 + ni * 16 + lane15;
    bOff[ni] = r * 64 + ((lg ^ CFUN(r)) * 16);
  }

  f32x4 acc[MF][4];
#pragma unroll
  for (int mi = 0; mi < MF; mi++)
#pragma unroll
    for (int ni = 0; ni < 4; ni++) acc[mi][ni] = (f32x4){0.f, 0.f, 0.f, 0.f};

  auto stage = [&](int buf, int t) {
    const size_t kb = (size_t)t * 64;
    cp16(smem + buf * ASZ + w * 1024, aSrc0 + kb);
    if constexpr (BM == 128) cp16(smem + buf * ASZ + 4096 + w * 1024, aSrc1 + kb);
    cp16(smem + 2 * ASZ + buf * 8192 + w * 1024, bSrc0 + kb);
    cp16(smem + 2 * ASZ + buf * 8192 + 4096 + w * 1024, bSrc1 + kb);
  };
  auto compute = [&](int buf) {
    const char* ab = smem + buf * ASZ;
    const char* bb = smem + 2 * ASZ + buf * 8192;
    bf16x8 af[MF], bfr[4];
#pragma unroll
    for (int mi = 0; mi < MF; mi++) af[mi] = *(const bf16x8*)(ab + aOff[mi]);
#pragma unroll
    for (int ni = 0; ni < 4; ni++) bfr[ni] = *(const bf16x8*)(bb + bOff[ni]);
#pragma unroll
    for (int mi = 0; mi < MF; mi++)
#pragma unroll
      for (int ni = 0; ni < 4; ni++)
        acc[mi][ni] = __builtin_amdgcn_mfma_f32_16x16x32_bf16(
            af[mi], bfr[ni], acc[mi][ni], 0, 0, 0);
  };

  const int nk = K >> 5;                 // always even (24 or 96)
  stage(0, 0);
  __syncthreads();
  for (int t = 0; t < nk; t += 2) {
    if (t + 1 < nk) stage(1, t + 1);
    compute(0);
    __syncthreads();
    if (t + 2 < nk) stage(0, t + 2);
    compute(1);
    __syncthreads();
  }

#pragma unroll
  for (int ni = 0; ni < 4; ni++) {
    const int col = n0 + wc * 64 + ni * 16 + lane15;
    const float bv = bias[col];
#pragma unroll
    for (int mi = 0; mi < MF; mi++) {
      const int rowb = m0 + wr * (BM / 2) + mi * 16 + lg * 4;
      if constexpr (EPI == 6) {
        if (col < 2304) {
#pragma unroll
          for (int j = 0; j < 4; j++)
            Cb[(size_t)(rowb + j) * 2304 + col] = __float2bfloat16(acc[mi][ni][j] + bv);
        } else if (col < 3072) {
          ushort4 pk;
          pk.x = f2bf(acc[mi][ni][0] + bv);
          pk.y = f2bf(acc[mi][ni][1] + bv);
          pk.z = f2bf(acc[mi][ni][2] + bv);
          pk.w = f2bf(acc[mi][ni][3] + bv);
          const int bq = rowb >> 10, s = rowb & (S_ - 1);
          *reinterpret_cast<ushort4*>(
              (unsigned short*)Cb2 + ((size_t)(bq * 768 + (col - 2304))) * S_ + s) = pk;
        } else {
#pragma unroll
          for (int j = 0; j < 4; j++)
            Cb3[(size_t)(rowb + j) * 1536 + (col - 3072)] =
                __float2bfloat16(acc[mi][ni][j] + bv);
        }
      } else {
#pragma unroll
        for (int j = 0; j < 4; j++) {
          const int row = rowb + j;
          float v = acc[mi][ni][j] + bv;
          if constexpr (EPI == 1) v += resid[(size_t)row * N + col];
          if constexpr (EPI == 2) {
            v = 0.5f * v * (1.0f + erff(v * 0.70710678118654752f));
            Cb[(size_t)row * N + col] = __float2bfloat16(v);
          } else if constexpr (EPI == 3) {
            Cb[(size_t)row * N + col] = __float2bfloat16(v);
          } else {
            Cf[(size_t)row * N + col] = v;
          }
        }
      }
    }
  }
}

// ---------------------------------------------------------------- flash attention
// qkv [BS][2304] = q|k|qc (bf16). vT [B*768][S] bf16. memkv [L][BS][1536] = ksh|vsh.
__global__ __launch_bounds__(256) void k_attn(
    const bf16* __restrict__ qkv, const bf16* __restrict__ vT,
    const bf16* __restrict__ memkv, bf16* __restrict__ ctx, int layer) {
  const int bh = blockIdx.x;
  const int b = bh / H_, h = bh % H_;
  const int qt = (int)gridDim.y - 1 - (int)blockIdx.y;   // big q first
  const int tid = threadIdx.x;
  const int w = tid >> 6, l = tid & 63;
  const int lane15 = l & 15, lg = l >> 4;
  const float inv = 0.125f;

  __shared__ char plds[4][2048];     // per-wave P tile, 16 rows x 128B, XOR-swz
  __shared__ float wlp[4][16][16];   // per-wave memory logits
  char* pl = plds[w];

  const int qrow0 = qt * 64 + w * 16;
  const size_t rowA = (size_t)(b * S_ + qrow0 + lane15);
  const bf16* qp = qkv + rowA * 2304 + h * 64 + lg * 8;
  const bf16x8 qf0 = *(const bf16x8*)(qp);
  const bf16x8 qf1 = *(const bf16x8*)(qp + 32);

  const bf16* kbase = qkv + (size_t)(b * S_) * 2304 + 768 + h * 64 + lg * 8;
  const bf16* vbase = vT + ((size_t)(b * 768 + h * 64 + lane15)) * S_;

  float mrow[4], dsum[4];
  f32x4 acc[4];
#pragma unroll
  for (int j = 0; j < 4; j++) { mrow[j] = -INFINITY; dsum[j] = 0.f; }
#pragma unroll
  for (int ni = 0; ni < 4; ni++) acc[ni] = (f32x4){0.f, 0.f, 0.f, 0.f};

  const int ntile = ((qrow0 + 15) >> 6) + 1;
  for (int kt64 = 0; kt64 < ntile; kt64++) {
    const int k0 = kt64 * 64;
    f32x4 sc[4];
#pragma unroll
    for (int kt = 0; kt < 4; kt++) {
      const bf16* kp = kbase + (size_t)(k0 + kt * 16 + lane15) * 2304;
      bf16x8 kf0 = *(const bf16x8*)(kp);
      bf16x8 kf1 = *(const bf16x8*)(kp + 32);
      f32x4 z = (f32x4){0.f, 0.f, 0.f, 0.f};
      z = __builtin_amdgcn_mfma_f32_16x16x32_bf16(qf0, kf0, z, 0, 0, 0);
      sc[kt] = __builtin_amdgcn_mfma_f32_16x16x32_bf16(qf1, kf1, z, 0, 0, 0);
    }
    float tmax[4];
#pragma unroll
    for (int j = 0; j < 4; j++) tmax[j] = -INFINITY;
#pragma unroll
    for (int kt = 0; kt < 4; kt++) {
      const int kabs = k0 + kt * 16 + lane15;
#pragma unroll
      for (int j = 0; j < 4; j++) {
        const int qabs = qrow0 + lg * 4 + j;
        float v = (kabs <= qabs) ? sc[kt][j] * inv : -INFINITY;
        sc[kt][j] = v;
        tmax[j] = fmaxf(tmax[j], v);
      }
    }
#pragma unroll
    for (int off = 1; off < 16; off <<= 1)
#pragma unroll
      for (int j = 0; j < 4; j++) tmax[j] = fmaxf(tmax[j], __shfl_xor(tmax[j], off, 16));

    float psum[4];
#pragma unroll
    for (int j = 0; j < 4; j++) {
      const float mnew = fmaxf(mrow[j], tmax[j]);
      const float alpha = __expf(mrow[j] - mnew);
      mrow[j] = mnew;
      dsum[j] *= alpha;
#pragma unroll
      for (int ni = 0; ni < 4; ni++) acc[ni][j] *= alpha;
      psum[j] = 0.f;
    }
#pragma unroll
    for (int kt = 0; kt < 4; kt++) {
      const int gsl = kt * 2 + (lane15 >> 3);
      const int ebyte = (lane15 & 7) * 2;
#pragma unroll
      for (int j = 0; j < 4; j++) {
        const float p = __expf(sc[kt][j] - mrow[j]);
        psum[j] += p;
        const int r = lg * 4 + j;
        *(unsigned short*)(pl + r * 128 + ((gsl ^ (r & 7)) << 4) + ebyte) = f2bf(p);
      }
    }
#pragma unroll
    for (int off = 1; off < 16; off <<= 1)
#pragma unroll
      for (int j = 0; j < 4; j++) psum[j] += __shfl_xor(psum[j], off, 16);
#pragma unroll
    for (int j = 0; j < 4; j++) dsum[j] += psum[j];

#pragma unroll
    for (int ks = 0; ks < 2; ks++) {
      bf16x8 pa = *(const bf16x8*)(pl + lane15 * 128 +
                                   ((((ks << 2) + lg) ^ (lane15 & 7)) << 4));
      const bf16* vp = vbase + k0 + ks * 32 + lg * 8;
#pragma unroll
      for (int ni = 0; ni < 4; ni++) {
        bf16x8 vf = *(const bf16x8*)(vp + (size_t)ni * 16 * S_);
        acc[ni] = __builtin_amdgcn_mfma_f32_16x16x32_bf16(pa, vf, acc[ni], 0, 0, 0);
      }
    }
  }

  // ---- memory (per-position k_col/v_col of previous layers)
  const int r4 = lg * 4;
  if (lane15 < layer) {
    const int ml = lane15;
#pragma unroll
    for (int j = 0; j < 4; j++) {
      const size_t rowB = (size_t)(b * S_) + qrow0 + r4 + j;
      const bf16* qc = qkv + rowB * 2304 + 1536 + h * 64;
      const bf16* mk = memkv + ((size_t)ml * BS_ + rowB) * 1536 + h * 64;
      float d_ = 0.f;
#pragma unroll
      for (int t = 0; t < 8; t++) {
        bf16x8 qv = *(const bf16x8*)(qc + t * 8);
        bf16x8 kv = *(const bf16x8*)(mk + t * 8);
#pragma unroll
        for (int e = 0; e < 8; e++)
          d_ += bf2f((unsigned short)qv[e]) * bf2f((unsigned short)kv[e]);
      }
      wlp[w][r4 + j][ml] = d_ * inv;
    }
  }
  if (layer > 0) {
#pragma unroll
    for (int j = 0; j < 4; j++) {
      const int r = r4 + j;
      float mm = -INFINITY;
      for (int ml = 0; ml < layer; ml++) mm = fmaxf(mm, wlp[w][r][ml]);
      const float mnew = fmaxf(mrow[j], mm);
      const float alpha = __expf(mrow[j] - mnew);
      mrow[j] = mnew;
      dsum[j] *= alpha;
#pragma unroll
      for (int ni = 0; ni < 4; ni++) acc[ni][j] *= alpha;
      const size_t rowB = (size_t)(b * S_) + qrow0 + r;
      for (int ml = 0; ml < layer; ml++) {
        const float p = __expf(wlp[w][r][ml] - mnew);
        dsum[j] += p;
        const unsigned short* mv = (const unsigned short*)(memkv +
            ((size_t)ml * BS_ + rowB) * 1536 + 768 + h * 64 + lane15);
#pragma unroll
        for (int ni = 0; ni < 4; ni++)
          acc[ni][j] += p * bf2f(mv[ni * 16]);
      }
    }
  }

#pragma unroll
  for (int j = 0; j < 4; j++) {
    const float rd = 1.f / dsum[j];
    const size_t rowB = (size_t)(b * S_) + qrow0 + r4 + j;
    bf16* cp = ctx + rowB * 768 + h * 64 + lane15;
#pragma unroll
    for (int ni = 0; ni < 4; ni++)
      cp[ni * 16] = __float2bfloat16(acc[ni][j] * rd);
  }
}

// ---------------------------------------------------------------- launch
extern "C" void kernel_launch(void* const* d_in, const int* in_sizes, int n_in,
                              void* d_out, int out_size, void* d_ws, size_t ws_size,
                              hipStream_t stream) {
  const int*   tokens  = (const int*)d_in[0];
  const float* tok_emb = (const float*)d_in[1];
  const float* pos_emb = (const float*)d_in[2];
  const float *Wq_row, *Wk_row, *Wv_row, *Wq_col, *Wo;
  const float *bq_row, *bk_row, *bv_row, *bq_col, *bo;
  if (in_sizes[4] == L_ * D_ * D_) {  // dict order
    Wq_row = (const float*)d_in[3];  Wk_row = (const float*)d_in[4];
    Wv_row = (const float*)d_in[5];  Wq_col = (const float*)d_in[6];
    Wo     = (const float*)d_in[7];
    bq_row = (const float*)d_in[8];  bk_row = (const float*)d_in[9];
    bv_row = (const float*)d_in[10]; bq_col = (const float*)d_in[11];
    bo     = (const float*)d_in[12];
  } else {  // signature order fallback
    Wq_row = (const float*)d_in[3];  bq_row = (const float*)d_in[4];
    Wk_row = (const float*)d_in[5];  bk_row = (const float*)d_in[6];
    Wv_row = (const float*)d_in[7];  bv_row = (const float*)d_in[8];
    Wq_col = (const float*)d_in[9];  bq_col = (const float*)d_in[10];
    Wo     = (const float*)d_in[11]; bo     = (const float*)d_in[12];
  }
  const float* ln1_g = (const float*)d_in[13]; const float* ln1_b = (const float*)d_in[14];
  const float* ln2_g = (const float*)d_in[15]; const float* ln2_b = (const float*)d_in[16];
  const float* W1    = (const float*)d_in[17]; const float* b1    = (const float*)d_in[18];
  const float* W2    = (const float*)d_in[19]; const float* b2    = (const float*)d_in[20];
  const float* Wk_sh = (const float*)d_in[21]; const float* bk_sh = (const float*)d_in[22];
  const float* Wv_sh = (const float*)d_in[23]; const float* bv_sh = (const float*)d_in[24];
  const float* lnf_g = (const float*)d_in[25]; const float* lnf_b = (const float*)d_in[26];
  const float* Whead = (const float*)d_in[27]; const float* bhead = (const float*)d_in[28];

  // ---- workspace carve-up
  char* p = (char*)d_ws;
  float* x      = (float*)p; p += (size_t)BS_ * D_ * 4;
  bf16*  h_bf   = (bf16*)p;  p += (size_t)BS_ * D_ * 2;
  bf16*  qkv3   = (bf16*)p;  p += (size_t)BS_ * 2304 * 2;
  bf16*  vTb    = (bf16*)p;  p += (size_t)B_ * 768 * S_ * 2;
  bf16*  memkv  = (bf16*)p;  p += (size_t)L_ * BS_ * 1536 * 2;
  bf16*  ctx_bf = (bf16*)p;  p += (size_t)BS_ * D_ * 2;
  bf16*  mlp_bf = (bf16*)p;  p += (size_t)BS_ * DFF_ * 2;
  float* b6cat  = (float*)p; p += (size_t)L_ * 4608 * 4;
  bf16* tW6    = (bf16*)p; p += (size_t)L_ * 4608 * D_ * 2;   // q|k|qc|v|ksh|vsh
  bf16* tWo    = (bf16*)p; p += (size_t)L_ * D_ * D_ * 2;
  bf16* tW1    = (bf16*)p; p += (size_t)L_ * DFF_ * D_ * 2;
  bf16* tW2    = (bf16*)p; p += (size_t)L_ * D_ * DFF_ * 2;
  bf16* tWhead = (bf16*)p; p += (size_t)V_ * D_ * 2;

  // ---- weight conversion (transposed bf16), bias concat
  dim3 tb(32, 8);
  const size_t DD = (size_t)D_ * D_;
  const size_t W6S = (size_t)4608 * 768;
  k_w2bf_t<<<dim3(24, 24, L_), tb, 0, stream>>>(Wq_row, tW6,              768, 768, DD, W6S);
  k_w2bf_t<<<dim3(24, 24, L_), tb, 0, stream>>>(Wk_row, tW6 + 768 * 768,  768, 768, DD, W6S);
  k_w2bf_t<<<dim3(24, 24, L_), tb, 0, stream>>>(Wq_col, tW6 + 1536 * 768, 768, 768, DD, W6S);
  k_w2bf_t<<<dim3(24, 24, L_), tb, 0, stream>>>(Wv_row, tW6 + 2304 * 768, 768, 768, DD, W6S);
  k_w2bf_t<<<dim3(24, 24, L_), tb, 0, stream>>>(Wk_sh,  tW6 + 3072 * 768, 768, 768, 0, W6S);
  k_w2bf_t<<<dim3(24, 24, L_), tb, 0, stream>>>(Wv_sh,  tW6 + 3840 * 768, 768, 768, 0, W6S);
  k_w2bf_t<<<dim3(24, 24, L_), tb, 0, stream>>>(Wo,     tWo, 768, 768, DD, DD);
  k_w2bf_t<<<dim3(96, 24, L_), tb, 0, stream>>>(W1, tW1, 768, 3072, (size_t)768 * 3072, (size_t)3072 * 768);
  k_w2bf_t<<<dim3(24, 96, L_), tb, 0, stream>>>(W2, tW2, 3072, 768, (size_t)768 * 3072, (size_t)768 * 3072);
  k_w2bf_t<<<dim3(1000, 24, 1), tb, 0, stream>>>(Whead, tWhead, 768, 32000, 0, 0);
  k_bcat<<<dim3(144), 256, 0, stream>>>(bq_row, bk_row, bq_col, bv_row, bk_sh, bv_sh, b6cat);

  k_embed<<<dim3((BS_ * D_) / 256), 256, 0, stream>>>(tokens, tok_emb, pos_emb, x);

  for (int i = 0; i < L_; i++) {
    k_ln<<<dim3(BS_), 256, 0, stream>>>(x, ln1_g + i * D_, ln1_b + i * D_, h_bf);
    k_bgemm<128, 6><<<dim3(576), 256, 0, stream>>>(
        h_bf, tW6 + (size_t)i * W6S, b6cat + (size_t)i * 4608,
        nullptr, nullptr, qkv3, vTb, memkv + (size_t)i * BS_ * 1536,
        16, BS_, 4608, 768);
    k_attn<<<dim3(B_ * H_, S_ / 64), 256, 0, stream>>>(qkv3, vTb, memkv, ctx_bf, i);
    k_bgemm<64, 1><<<dim3(192), 256, 0, stream>>>(
        ctx_bf, tWo + (size_t)i * DD, bo + i * D_, x, x, nullptr, nullptr, nullptr,
        32, BS_, 768, 768);
    k_ln<<<dim3(BS_), 256, 0, stream>>>(x, ln2_g + i * D_, ln2_b + i * D_, h_bf);
    k_bgemm<128, 2><<<dim3(384), 256, 0, stream>>>(
        h_bf, tW1 + (size_t)i * 3072 * 768, b1 + (size_t)i * DFF_,
        nullptr, nullptr, mlp_bf, nullptr, nullptr, 16, BS_, 3072, 768);
    k_bgemm<64, 1><<<dim3(192), 256, 0, stream>>>(
        mlp_bf, tW2 + (size_t)i * 768 * 3072, b2 + i * D_, x, x, nullptr, nullptr,
        nullptr, 32, BS_, 768, 3072);
  }
  k_ln<<<dim3(BS_), 256, 0, stream>>>(x, lnf_g, lnf_b, h_bf);
  k_bgemm<128, 0><<<dim3(4000), 256, 0, stream>>>(
      h_bf, tWhead, bhead, nullptr, (float*)d_out, nullptr, nullptr, nullptr,
      16, BS_, V_, 768);
}

// Round 6
// 1883.649 us; speedup vs baseline: 4.8767x; 1.0561x over previous
//
#include <hip/hip_runtime.h>
#include <hip/hip_bf16.h>
#include <math.h>

#define L_   8
#define D_   768
#define H_   12
#define V_   32000
#define B_   2
#define S_   1024
#define HD_  64
#define BS_  2048      // B_*S_
#define DFF_ 3072      // MR*D

typedef __hip_bfloat16 bf16;
typedef __attribute__((ext_vector_type(8))) short bf16x8;
typedef __attribute__((ext_vector_type(4))) float f32x4;

#define CFUN(r) ((((r) & 3)) ^ (((r) >> 2) & 3))

__device__ __forceinline__ void cp16(void* lds, const void* g) {
  __builtin_amdgcn_global_load_lds(
      (const __attribute__((address_space(1))) void*)g,
      (__attribute__((address_space(3))) void*)lds, 16, 0, 0);
}

__device__ __forceinline__ unsigned short f2bf(float v) {
  __hip_bfloat16 h = __float2bfloat16(v);
  return *reinterpret_cast<unsigned short*>(&h);
}
__device__ __forceinline__ float bf2f(unsigned short u) {
  return __uint_as_float(((unsigned)u) << 16);
}

// ---------------------------------------------------------------- embedding
__global__ __launch_bounds__(256) void k_embed(const int* __restrict__ tokens,
    const float* __restrict__ tok_emb, const float* __restrict__ pos_emb,
    float* __restrict__ x) {
  int idx = blockIdx.x * 256 + threadIdx.x;
  int row = idx / D_;
  int d   = idx - row * D_;
  int s   = row & (S_ - 1);
  int t   = tokens[row];
  x[idx] = tok_emb[(size_t)t * D_ + d] + pos_emb[(size_t)s * D_ + d];
}

// ---------------------------------------------------------------- layernorm -> bf16
__global__ __launch_bounds__(256) void k_ln(const float* __restrict__ x,
    const float* __restrict__ g, const float* __restrict__ b,
    bf16* __restrict__ out) {
  int row = blockIdx.x;
  const float* xr = x + (size_t)row * D_;
  int t = threadIdx.x;
  float v0 = xr[t], v1 = xr[t + 256], v2 = xr[t + 512];
  float s  = v0 + v1 + v2;
  float s2 = v0 * v0 + v1 * v1 + v2 * v2;
#pragma unroll
  for (int off = 32; off; off >>= 1) {
    s  += __shfl_down(s, off);
    s2 += __shfl_down(s2, off);
  }
  __shared__ float rs[4], rs2[4];
  __shared__ float mean_s, rstd_s;
  int wid = t >> 6;
  if ((t & 63) == 0) { rs[wid] = s; rs2[wid] = s2; }
  __syncthreads();
  if (t == 0) {
    float S1 = rs[0] + rs[1] + rs[2] + rs[3];
    float S2 = rs2[0] + rs2[1] + rs2[2] + rs2[3];
    float m  = S1 / D_;
    float var = S2 / D_ - m * m;
    mean_s = m;
    rstd_s = rsqrtf(var + 1e-5f);
  }
  __syncthreads();
  float m = mean_s, r = rstd_s;
  bf16* orow = out + (size_t)row * D_;
  orow[t]       = __float2bfloat16((v0 - m) * r * g[t]       + b[t]);
  orow[t + 256] = __float2bfloat16((v1 - m) * r * g[t + 256] + b[t + 256]);
  orow[t + 512] = __float2bfloat16((v2 - m) * r * g[t + 512] + b[t + 512]);
}

// ------------------------------------------------- weight convert + transpose
// W[K][N] f32 -> Wt[N][K] bf16 (slice-capable). grid (N/32, K/32, nz).
// ils==0 replicates the same source into every z slice.
__global__ __launch_bounds__(256) void k_w2bf_t(const float* __restrict__ W,
    bf16* __restrict__ Wt, int K, int N, size_t ils, size_t ols) {
  __shared__ float t[32][33];
  const float* Wm = W + (size_t)blockIdx.z * ils;
  bf16* Wtm = Wt + (size_t)blockIdx.z * ols;
  int n0 = blockIdx.x * 32, k0 = blockIdx.y * 32;
  int tx = threadIdx.x;
  for (int i = threadIdx.y; i < 32; i += 8)
    t[i][tx] = Wm[(size_t)(k0 + i) * N + n0 + tx];
  __syncthreads();
  for (int i = threadIdx.y; i < 32; i += 8)
    Wtm[(size_t)(n0 + i) * K + k0 + tx] = __float2bfloat16(t[tx][i]);
}

// ---------------------------------------------------------------- bias concat
// b6cat[L][4608] = bq|bk|bqc|bv|bksh|bvsh
__global__ __launch_bounds__(256) void k_bcat(const float* __restrict__ bq,
    const float* __restrict__ bk, const float* __restrict__ bqc,
    const float* __restrict__ bv, const float* __restrict__ bksh,
    const float* __restrict__ bvsh, float* __restrict__ b6) {
  int idx = blockIdx.x * 256 + threadIdx.x;
  if (idx >= L_ * 4608) return;
  int l = idx / 4608, c = idx - l * 4608;
  float v = (c < 768)  ? bq[l * 768 + c]
          : (c < 1536) ? bk[l * 768 + c - 768]
          : (c < 2304) ? bqc[l * 768 + c - 1536]
          : (c < 3072) ? bv[l * 768 + c - 2304]
          : (c < 3840) ? bksh[c - 3072]
                       : bvsh[c - 3840];
  b6[idx] = v;
}

// ---------------------------------------------------------------- bf16 MFMA GEMM
// C[M,N] = A[M,K](bf16) @ Wt[N,K](bf16)^T + bias. BMx128 tile, BK=32, 4 waves.
// 3-buffer circular LDS pipeline, depth-2 prefetch, counted vmcnt + raw
// s_barrier (T4): the newest stage's loads stay in flight across the barrier.
// 1-D grid, chunked XCD remap, m-fast decode (W panels pinned to one XCD L2).
// EPI: 0 f32+bias; 1 f32+bias+resid; 2 bf16+bias+gelu; 3 bf16+bias;
//      6 fused routing: col<2304 -> qkv [row][2304]; <3072 -> vT transposed;
//        else -> memkv [row][1536].
template <int BM, int EPI>
__global__ __launch_bounds__(256) void k_bgemm(
    const bf16* __restrict__ A, const bf16* __restrict__ Wt,
    const float* __restrict__ bias, const float* __restrict__ resid,
    float* __restrict__ Cf, bf16* __restrict__ Cb, bf16* __restrict__ Cb2,
    bf16* __restrict__ Cb3, int NM, int M, int N, int K) {
  constexpr int ASZ = BM * 64;               // bytes per A sub-buffer
  constexpr int BSTRIDE = ASZ + 8192;        // A + B per pipeline buffer
  constexpr int MF = BM / 32;
  __shared__ __align__(16) char smem[3 * BSTRIDE];
  const int tid = threadIdx.x;
  const int l = tid & 63, w = tid >> 6;
  const int wr = w >> 1, wc = w & 1;

  // chunked XCD remap (nwg % 8 == 0), then m-fast decode
  const int nwg = (int)gridDim.x;
  int id = (int)blockIdx.x;
  id = (id & 7) * (nwg >> 3) + (id >> 3);
  const int m0 = (id % NM) * BM;
  const int n0 = (id / NM) * 128;

  const int lane15 = l & 15, lg = l >> 4;

  const int r0 = tid >> 2, p0 = tid & 3;
  const int r1 = 64 + r0;
  const char* aSrc0 = (const char*)(A  + (size_t)(m0 + r0) * K) + ((p0 ^ CFUN(r0)) * 16);
  const char* aSrc1 = (const char*)(A  + (size_t)(m0 + r1) * K) + ((p0 ^ CFUN(r1)) * 16);
  const char* bSrc0 = (const char*)(Wt + (size_t)(n0 + r0) * K) + ((p0 ^ CFUN(r0)) * 16);
  const char* bSrc1 = (const char*)(Wt + (size_t)(n0 + r1) * K) + ((p0 ^ CFUN(r1)) * 16);

  int aOff[MF], bOff[4];
#pragma unroll
  for (int mi = 0; mi < MF; mi++) {
    int r = wr * (BM / 2) + mi * 16 + lane15;
    aOff[mi] = r * 64 + ((lg ^ CFUN(r)) * 16);
  }
#pragma unroll
  for (int ni = 0; ni < 4; ni++) {
    int r = wc * 64 + ni * 16 + lane15;
    bOff[ni] = ASZ + r * 64 + ((lg ^ CFUN(r)) * 16);
  }

  f32x4 acc[MF][4];
#pragma unroll
  for (int mi = 0; mi < MF; mi++)
#pragma unroll
    for (int ni = 0; ni < 4; ni++) acc[mi][ni] = (f32x4){0.f, 0.f, 0.f, 0.f};

  auto stage = [&](int buf, int t) {
    const size_t kb = (size_t)t * 64;
    char* base = smem + buf * BSTRIDE;
    cp16(base + w * 1024, aSrc0 + kb);
    if constexpr (BM == 128) cp16(base + 4096 + w * 1024, aSrc1 + kb);
    cp16(base + ASZ + w * 1024, bSrc0 + kb);
    cp16(base + ASZ + 4096 + w * 1024, bSrc1 + kb);
  };
  auto compute = [&](int buf) {
    const char* base = smem + buf * BSTRIDE;
    bf16x8 af[MF], bfr[4];
#pragma unroll
    for (int mi = 0; mi < MF; mi++) af[mi] = *(const bf16x8*)(base + aOff[mi]);
#pragma unroll
    for (int ni = 0; ni < 4; ni++) bfr[ni] = *(const bf16x8*)(base + bOff[ni]);
    __builtin_amdgcn_s_setprio(1);
#pragma unroll
    for (int mi = 0; mi < MF; mi++)
#pragma unroll
      for (int ni = 0; ni < 4; ni++)
        acc[mi][ni] = __builtin_amdgcn_mfma_f32_16x16x32_bf16(
            af[mi], bfr[ni], acc[mi][ni], 0, 0, 0);
    __builtin_amdgcn_s_setprio(0);
  };

  const int nk = K >> 5;                 // 24 or 96 (always >= 3)
  stage(0, 0);
  stage(1, 1);
  int buf = 0;
  for (int t = 0; t < nk; t++) {
    // wait until MY stage(t) loads have landed; stage(t+1) may stay in flight
    if (t + 1 < nk) {
      if constexpr (BM == 128) asm volatile("s_waitcnt vmcnt(4)" ::: "memory");
      else                     asm volatile("s_waitcnt vmcnt(3)" ::: "memory");
    } else {
      asm volatile("s_waitcnt vmcnt(0)" ::: "memory");
    }
    // all waves: stage(t) landed AND compute(t-1) consumed -> buffer (t+2)%3 free
    __builtin_amdgcn_s_barrier();
    if (t + 2 < nk) {
      int nb = buf + 2; if (nb >= 3) nb -= 3;
      stage(nb, t + 2);
    }
    compute(buf);
    buf = (buf == 2) ? 0 : buf + 1;
  }

#pragma unroll
  for (int ni = 0; ni < 4; ni++) {
    const int col = n0 + wc * 64 + ni * 16 + lane15;
    const float bv = bias[col];
#pragma unroll
    for (int mi = 0; mi < MF; mi++) {
      const int rowb = m0 + wr * (BM / 2) + mi * 16 + lg * 4;
      if constexpr (EPI == 6) {
        if (col < 2304) {
#pragma unroll
          for (int j = 0; j < 4; j++)
            Cb[(size_t)(rowb + j) * 2304 + col] = __float2bfloat16(acc[mi][ni][j] + bv);
        } else if (col < 3072) {
          ushort4 pk;
          pk.x = f2bf(acc[mi][ni][0] + bv);
          pk.y = f2bf(acc[mi][ni][1] + bv);
          pk.z = f2bf(acc[mi][ni][2] + bv);
          pk.w = f2bf(acc[mi][ni][3] + bv);
          const int bq = rowb >> 10, s = rowb & (S_ - 1);
          *reinterpret_cast<ushort4*>(
              (unsigned short*)Cb2 + ((size_t)(bq * 768 + (col - 2304))) * S_ + s) = pk;
        } else {
#pragma unroll
          for (int j = 0; j < 4; j++)
            Cb3[(size_t)(rowb + j) * 1536 + (col - 3072)] =
                __float2bfloat16(acc[mi][ni][j] + bv);
        }
      } else {
#pragma unroll
        for (int j = 0; j < 4; j++) {
          const int row = rowb + j;
          float v = acc[mi][ni][j] + bv;
          if constexpr (EPI == 1) v += resid[(size_t)row * N + col];
          if constexpr (EPI == 2) {
            v = 0.5f * v * (1.0f + erff(v * 0.70710678118654752f));
            Cb[(size_t)row * N + col] = __float2bfloat16(v);
          } else if constexpr (EPI == 3) {
            Cb[(size_t)row * N + col] = __float2bfloat16(v);
          } else {
            Cf[(size_t)row * N + col] = v;
          }
        }
      }
    }
  }
}

// ---------------------------------------------------------------- flash attention
// qkv [BS][2304] = q|k|qc (bf16). vT [B*768][S] bf16. memkv [L][BS][1536] = ksh|vsh.
__global__ __launch_bounds__(256) void k_attn(
    const bf16* __restrict__ qkv, const bf16* __restrict__ vT,
    const bf16* __restrict__ memkv, bf16* __restrict__ ctx, int layer) {
  const int bh = blockIdx.x;
  const int b = bh / H_, h = bh % H_;
  const int qt = (int)gridDim.y - 1 - (int)blockIdx.y;   // big q first
  const int tid = threadIdx.x;
  const int w = tid >> 6, l = tid & 63;
  const int lane15 = l & 15, lg = l >> 4;
  const float inv = 0.125f;

  __shared__ char plds[4][2048];     // per-wave P tile, 16 rows x 128B, XOR-swz
  __shared__ float wlp[4][16][16];   // per-wave memory logits
  char* pl = plds[w];

  const int qrow0 = qt * 64 + w * 16;
  const size_t rowA = (size_t)(b * S_ + qrow0 + lane15);
  const bf16* qp = qkv + rowA * 2304 + h * 64 + lg * 8;
  const bf16x8 qf0 = *(const bf16x8*)(qp);
  const bf16x8 qf1 = *(const bf16x8*)(qp + 32);

  const bf16* kbase = qkv + (size_t)(b * S_) * 2304 + 768 + h * 64 + lg * 8;
  const bf16* vbase = vT + ((size_t)(b * 768 + h * 64 + lane15)) * S_;

  float mrow[4], dsum[4];
  f32x4 acc[4];
#pragma unroll
  for (int j = 0; j < 4; j++) { mrow[j] = -INFINITY; dsum[j] = 0.f; }
#pragma unroll
  for (int ni = 0; ni < 4; ni++) acc[ni] = (f32x4){0.f, 0.f, 0.f, 0.f};

  const int ntile = ((qrow0 + 15) >> 6) + 1;
  for (int kt64 = 0; kt64 < ntile; kt64++) {
    const int k0 = kt64 * 64;
    f32x4 sc[4];
#pragma unroll
    for (int kt = 0; kt < 4; kt++) {
      const bf16* kp = kbase + (size_t)(k0 + kt * 16 + lane15) * 2304;
      bf16x8 kf0 = *(const bf16x8*)(kp);
      bf16x8 kf1 = *(const bf16x8*)(kp + 32);
      f32x4 z = (f32x4){0.f, 0.f, 0.f, 0.f};
      z = __builtin_amdgcn_mfma_f32_16x16x32_bf16(qf0, kf0, z, 0, 0, 0);
      sc[kt] = __builtin_amdgcn_mfma_f32_16x16x32_bf16(qf1, kf1, z, 0, 0, 0);
    }
    float tmax[4];
#pragma unroll
    for (int j = 0; j < 4; j++) tmax[j] = -INFINITY;
#pragma unroll
    for (int kt = 0; kt < 4; kt++) {
      const int kabs = k0 + kt * 16 + lane15;
#pragma unroll
      for (int j = 0; j < 4; j++) {
        const int qabs = qrow0 + lg * 4 + j;
        float v = (kabs <= qabs) ? sc[kt][j] * inv : -INFINITY;
        sc[kt][j] = v;
        tmax[j] = fmaxf(tmax[j], v);
      }
    }
#pragma unroll
    for (int off = 1; off < 16; off <<= 1)
#pragma unroll
      for (int j = 0; j < 4; j++) tmax[j] = fmaxf(tmax[j], __shfl_xor(tmax[j], off, 16));

    float psum[4];
#pragma unroll
    for (int j = 0; j < 4; j++) {
      const float mnew = fmaxf(mrow[j], tmax[j]);
      const float alpha = __expf(mrow[j] - mnew);
      mrow[j] = mnew;
      dsum[j] *= alpha;
#pragma unroll
      for (int ni = 0; ni < 4; ni++) acc[ni][j] *= alpha;
      psum[j] = 0.f;
    }
#pragma unroll
    for (int kt = 0; kt < 4; kt++) {
      const int gsl = kt * 2 + (lane15 >> 3);
      const int ebyte = (lane15 & 7) * 2;
#pragma unroll
      for (int j = 0; j < 4; j++) {
        const float p = __expf(sc[kt][j] - mrow[j]);
        psum[j] += p;
        const int r = lg * 4 + j;
        *(unsigned short*)(pl + r * 128 + ((gsl ^ (r & 7)) << 4) + ebyte) = f2bf(p);
      }
    }
#pragma unroll
    for (int off = 1; off < 16; off <<= 1)
#pragma unroll
      for (int j = 0; j < 4; j++) psum[j] += __shfl_xor(psum[j], off, 16);
#pragma unroll
    for (int j = 0; j < 4; j++) dsum[j] += psum[j];

#pragma unroll
    for (int ks = 0; ks < 2; ks++) {
      bf16x8 pa = *(const bf16x8*)(pl + lane15 * 128 +
                                   ((((ks << 2) + lg) ^ (lane15 & 7)) << 4));
      const bf16* vp = vbase + k0 + ks * 32 + lg * 8;
#pragma unroll
      for (int ni = 0; ni < 4; ni++) {
        bf16x8 vf = *(const bf16x8*)(vp + (size_t)ni * 16 * S_);
        acc[ni] = __builtin_amdgcn_mfma_f32_16x16x32_bf16(pa, vf, acc[ni], 0, 0, 0);
      }
    }
  }

  // ---- memory (per-position k_col/v_col of previous layers)
  const int r4 = lg * 4;
  if (lane15 < layer) {
    const int ml = lane15;
#pragma unroll
    for (int j = 0; j < 4; j++) {
      const size_t rowB = (size_t)(b * S_) + qrow0 + r4 + j;
      const bf16* qc = qkv + rowB * 2304 + 1536 + h * 64;
      const bf16* mk = memkv + ((size_t)ml * BS_ + rowB) * 1536 + h * 64;
      float d_ = 0.f;
#pragma unroll
      for (int t = 0; t < 8; t++) {
        bf16x8 qv = *(const bf16x8*)(qc + t * 8);
        bf16x8 kv = *(const bf16x8*)(mk + t * 8);
#pragma unroll
        for (int e = 0; e < 8; e++)
          d_ += bf2f((unsigned short)qv[e]) * bf2f((unsigned short)kv[e]);
      }
      wlp[w][r4 + j][ml] = d_ * inv;
    }
  }
  if (layer > 0) {
#pragma unroll
    for (int j = 0; j < 4; j++) {
      const int r = r4 + j;
      float mm = -INFINITY;
      for (int ml = 0; ml < layer; ml++) mm = fmaxf(mm, wlp[w][r][ml]);
      const float mnew = fmaxf(mrow[j], mm);
      const float alpha = __expf(mrow[j] - mnew);
      mrow[j] = mnew;
      dsum[j] *= alpha;
#pragma unroll
      for (int ni = 0; ni < 4; ni++) acc[ni][j] *= alpha;
      const size_t rowB = (size_t)(b * S_) + qrow0 + r;
      for (int ml = 0; ml < layer; ml++) {
        const float p = __expf(wlp[w][r][ml] - mnew);
        dsum[j] += p;
        const unsigned short* mv = (const unsigned short*)(memkv +
            ((size_t)ml * BS_ + rowB) * 1536 + 768 + h * 64 + lane15);
#pragma unroll
        for (int ni = 0; ni < 4; ni++)
          acc[ni][j] += p * bf2f(mv[ni * 16]);
      }
    }
  }

#pragma unroll
  for (int j = 0; j < 4; j++) {
    const float rd = 1.f / dsum[j];
    const size_t rowB = (size_t)(b * S_) + qrow0 + r4 + j;
    bf16* cp = ctx + rowB * 768 + h * 64 + lane15;
#pragma unroll
    for (int ni = 0; ni < 4; ni++)
      cp[ni * 16] = __float2bfloat16(acc[ni][j] * rd);
  }
}

// ---------------------------------------------------------------- launch
extern "C" void kernel_launch(void* const* d_in, const int* in_sizes, int n_in,
                              void* d_out, int out_size, void* d_ws, size_t ws_size,
                              hipStream_t stream) {
  const int*   tokens  = (const int*)d_in[0];
  const float* tok_emb = (const float*)d_in[1];
  const float* pos_emb = (const float*)d_in[2];
  const float *Wq_row, *Wk_row, *Wv_row, *Wq_col, *Wo;
  const float *bq_row, *bk_row, *bv_row, *bq_col, *bo;
  if (in_sizes[4] == L_ * D_ * D_) {  // dict order
    Wq_row = (const float*)d_in[3];  Wk_row = (const float*)d_in[4];
    Wv_row = (const float*)d_in[5];  Wq_col = (const float*)d_in[6];
    Wo     = (const float*)d_in[7];
    bq_row = (const float*)d_in[8];  bk_row = (const float*)d_in[9];
    bv_row = (const float*)d_in[10]; bq_col = (const float*)d_in[11];
    bo     = (const float*)d_in[12];
  } else {  // signature order fallback
    Wq_row = (const float*)d_in[3];  bq_row = (const float*)d_in[4];
    Wk_row = (const float*)d_in[5];  bk_row = (const float*)d_in[6];
    Wv_row = (const float*)d_in[7];  bv_row = (const float*)d_in[8];
    Wq_col = (const float*)d_in[9];  bq_col = (const float*)d_in[10];
    Wo     = (const float*)d_in[11]; bo     = (const float*)d_in[12];
  }
  const float* ln1_g = (const float*)d_in[13]; const float* ln1_b = (const float*)d_in[14];
  const float* ln2_g = (const float*)d_in[15]; const float* ln2_b = (const float*)d_in[16];
  const float* W1    = (const float*)d_in[17]; const float* b1    = (const float*)d_in[18];
  const float* W2    = (const float*)d_in[19]; const float* b2    = (const float*)d_in[20];
  const float* Wk_sh = (const float*)d_in[21]; const float* bk_sh = (const float*)d_in[22];
  const float* Wv_sh = (const float*)d_in[23]; const float* bv_sh = (const float*)d_in[24];
  const float* lnf_g = (const float*)d_in[25]; const float* lnf_b = (const float*)d_in[26];
  const float* Whead = (const float*)d_in[27]; const float* bhead = (const float*)d_in[28];

  // ---- workspace carve-up
  char* p = (char*)d_ws;
  float* x      = (float*)p; p += (size_t)BS_ * D_ * 4;
  bf16*  h_bf   = (bf16*)p;  p += (size_t)BS_ * D_ * 2;
  bf16*  qkv3   = (bf16*)p;  p += (size_t)BS_ * 2304 * 2;
  bf16*  vTb    = (bf16*)p;  p += (size_t)B_ * 768 * S_ * 2;
  bf16*  memkv  = (bf16*)p;  p += (size_t)L_ * BS_ * 1536 * 2;
  bf16*  ctx_bf = (bf16*)p;  p += (size_t)BS_ * D_ * 2;
  bf16*  mlp_bf = (bf16*)p;  p += (size_t)BS_ * DFF_ * 2;
  float* b6cat  = (float*)p; p += (size_t)L_ * 4608 * 4;
  bf16* tW6    = (bf16*)p; p += (size_t)L_ * 4608 * D_ * 2;   // q|k|qc|v|ksh|vsh
  bf16* tWo    = (bf16*)p; p += (size_t)L_ * D_ * D_ * 2;
  bf16* tW1    = (bf16*)p; p += (size_t)L_ * DFF_ * D_ * 2;
  bf16* tW2    = (bf16*)p; p += (size_t)L_ * D_ * DFF_ * 2;
  bf16* tWhead = (bf16*)p; p += (size_t)V_ * D_ * 2;

  // ---- weight conversion (transposed bf16), bias concat
  dim3 tb(32, 8);
  const size_t DD = (size_t)D_ * D_;
  const size_t W6S = (size_t)4608 * 768;
  k_w2bf_t<<<dim3(24, 24, L_), tb, 0, stream>>>(Wq_row, tW6,              768, 768, DD, W6S);
  k_w2bf_t<<<dim3(24, 24, L_), tb, 0, stream>>>(Wk_row, tW6 + 768 * 768,  768, 768, DD, W6S);
  k_w2bf_t<<<dim3(24, 24, L_), tb, 0, stream>>>(Wq_col, tW6 + 1536 * 768, 768, 768, DD, W6S);
  k_w2bf_t<<<dim3(24, 24, L_), tb, 0, stream>>>(Wv_row, tW6 + 2304 * 768, 768, 768, DD, W6S);
  k_w2bf_t<<<dim3(24, 24, L_), tb, 0, stream>>>(Wk_sh,  tW6 + 3072 * 768, 768, 768, 0, W6S);
  k_w2bf_t<<<dim3(24, 24, L_), tb, 0, stream>>>(Wv_sh,  tW6 + 3840 * 768, 768, 768, 0, W6S);
  k_w2bf_t<<<dim3(24, 24, L_), tb, 0, stream>>>(Wo,     tWo, 768, 768, DD, DD);
  k_w2bf_t<<<dim3(96, 24, L_), tb, 0, stream>>>(W1, tW1, 768, 3072, (size_t)768 * 3072, (size_t)3072 * 768);
  k_w2bf_t<<<dim3(24, 96, L_), tb, 0, stream>>>(W2, tW2, 3072, 768, (size_t)768 * 3072, (size_t)768 * 3072);
  k_w2bf_t<<<dim3(1000, 24, 1), tb, 0, stream>>>(Whead, tWhead, 768, 32000, 0, 0);
  k_bcat<<<dim3(144), 256, 0, stream>>>(bq_row, bk_row, bq_col, bv_row, bk_sh, bv_sh, b6cat);

  k_embed<<<dim3((BS_ * D_) / 256), 256, 0, stream>>>(tokens, tok_emb, pos_emb, x);

  for (int i = 0; i < L_; i++) {
    k_ln<<<dim3(BS_), 256, 0, stream>>>(x, ln1_g + i * D_, ln1_b + i * D_, h_bf);
    k_bgemm<128, 6><<<dim3(576), 256, 0, stream>>>(
        h_bf, tW6 + (size_t)i * W6S, b6cat + (size_t)i * 4608,
        nullptr, nullptr, qkv3, vTb, memkv + (size_t)i * BS_ * 1536,
        16, BS_, 4608, 768);
    k_attn<<<dim3(B_ * H_, S_ / 64), 256, 0, stream>>>(qkv3, vTb, memkv, ctx_bf, i);
    k_bgemm<64, 1><<<dim3(192), 256, 0, stream>>>(
        ctx_bf, tWo + (size_t)i * DD, bo + i * D_, x, x, nullptr, nullptr, nullptr,
        32, BS_, 768, 768);
    k_ln<<<dim3(BS_), 256, 0, stream>>>(x, ln2_g + i * D_, ln2_b + i * D_, h_bf);
    k_bgemm<128, 2><<<dim3(384), 256, 0, stream>>>(
        h_bf, tW1 + (size_t)i * 3072 * 768, b1 + (size_t)i * DFF_,
        nullptr, nullptr, mlp_bf, nullptr, nullptr, 16, BS_, 3072, 768);
    k_bgemm<64, 1><<<dim3(192), 256, 0, stream>>>(
        mlp_bf, tW2 + (size_t)i * 768 * 3072, b2 + i * D_, x, x, nullptr, nullptr,
        nullptr, 32, BS_, 768, 3072);
  }
  k_ln<<<dim3(BS_), 256, 0, stream>>>(x, lnf_g, lnf_b, h_bf);
  k_bgemm<128, 0><<<dim3(4000), 256, 0, stream>>>(
      h_bf, tWhead, bhead, nullptr, (float*)d_out, nullptr, nullptr, nullptr,
      16, BS_, V_, 768);
}